// Round 1
// baseline (487.733 us; speedup 1.0000x reference)
//
#include <hip/hip_runtime.h>
#include <cstdint>
#include <cstddef>

#define N_O 50000
#define N_Q 50000
#define NE  1600000
// LATENT=128, HEADS=4, HEAD_DIM=32

// ---------------------------------------------------------------------------
// pack: per-j 16-float struct for the edge MLP:
//  [0..3]=W1[0..3][j] [4..7]=W1[4..7][j] [8]=W1[8][j] [9]=b1[j]
//  [10..13]=W2[j][0..3] [14..15]=pad
// extras at float offset 2048: [0]=1/(2*sigma^2), [1..4]=b2[0..3]
// ---------------------------------------------------------------------------
__global__ void pack_kernel(const float* __restrict__ W1, const float* __restrict__ b1,
                            const float* __restrict__ W2, const float* __restrict__ b2,
                            const float* __restrict__ log_sigma, float* __restrict__ pack) {
    int j = threadIdx.x;
    if (j < 128) {
        float* p = pack + j * 16;
        #pragma unroll
        for (int i = 0; i < 9; ++i) p[i] = W1[i * 128 + j];
        p[9]  = b1[j];
        p[10] = W2[j * 4 + 0]; p[11] = W2[j * 4 + 1];
        p[12] = W2[j * 4 + 2]; p[13] = W2[j * 4 + 3];
        p[14] = 0.f; p[15] = 0.f;
    } else if (j == 128) {
        float sigma = expf(log_sigma[0]) + 1e-6f;
        pack[2048] = 1.0f / (2.0f * sigma * sigma);
        pack[2049] = b2[0]; pack[2050] = b2[1];
        pack[2051] = b2[2]; pack[2052] = b2[3];
        pack[2053] = 0.f; pack[2054] = 0.f; pack[2055] = 0.f;
    }
}

// ---------------------------------------------------------------------------
// rowptr: rp[q] = lower_bound(dst, q) for q in [0, N_Q]  (dst is sorted)
// ---------------------------------------------------------------------------
__global__ void rowptr_kernel(const int* __restrict__ dst, int* __restrict__ rp) {
    int q = blockIdx.x * blockDim.x + threadIdx.x;
    if (q > N_Q) return;
    int lo = 0, hi = NE;
    while (lo < hi) {
        int mid = (lo + hi) >> 1;
        if (dst[mid] < q) lo = mid + 1; else hi = mid;
    }
    rp[q] = lo;
}

// ---------------------------------------------------------------------------
// vproj: v = h_obs @ Wv + bv   [50000,128] = [50000,128]@[128,128]
// 64 rows per block, 256 threads, 4x8 outputs per thread.
// A staged in LDS (padded 132 to break bank aliasing), B read via float4
// global loads (Wv row is hot in L1 across the block's 4 waves).
// ---------------------------------------------------------------------------
__global__ __launch_bounds__(256) void vproj_kernel(const float* __restrict__ h,
                                                    const float* __restrict__ Wv,
                                                    const float* __restrict__ bv,
                                                    float* __restrict__ v) {
    __shared__ float Ash[64 * 132];
    int t = threadIdx.x;
    int n0 = blockIdx.x * 64;
    // stage A tile [64][128]
    #pragma unroll
    for (int rep = 0; rep < 8; ++rep) {
        int idx = rep * 256 + t;           // flat over [64][32] float4s
        int row = idx >> 5, c4 = (idx & 31) * 4;
        float4 val = make_float4(0.f, 0.f, 0.f, 0.f);
        if (n0 + row < N_O) val = *(const float4*)(h + (size_t)(n0 + row) * 128 + c4);
        float* d = &Ash[row * 132 + c4];
        d[0] = val.x; d[1] = val.y; d[2] = val.z; d[3] = val.w;
    }
    __syncthreads();

    int cg = t & 15, rg = t >> 4;
    int c0 = cg * 8, r0 = rg * 4;
    float acc[4][8];
    #pragma unroll
    for (int i = 0; i < 4; ++i)
        #pragma unroll
        for (int j = 0; j < 8; ++j) acc[i][j] = 0.f;

    const float4* Wv4 = (const float4*)Wv;
    for (int k = 0; k < 128; ++k) {
        float4 b0 = Wv4[k * 32 + cg * 2];
        float4 b1v = Wv4[k * 32 + cg * 2 + 1];
        float bb[8] = {b0.x, b0.y, b0.z, b0.w, b1v.x, b1v.y, b1v.z, b1v.w};
        #pragma unroll
        for (int i = 0; i < 4; ++i) {
            float a = Ash[(r0 + i) * 132 + k];
            #pragma unroll
            for (int j = 0; j < 8; ++j) acc[i][j] += a * bb[j];
        }
    }

    float bvv[8];
    #pragma unroll
    for (int j = 0; j < 8; ++j) bvv[j] = bv[c0 + j];
    #pragma unroll
    for (int i = 0; i < 4; ++i) {
        int n = n0 + r0 + i;
        if (n < N_O) {
            float4 o0 = make_float4(acc[i][0] + bvv[0], acc[i][1] + bvv[1],
                                    acc[i][2] + bvv[2], acc[i][3] + bvv[3]);
            float4 o1 = make_float4(acc[i][4] + bvv[4], acc[i][5] + bvv[5],
                                    acc[i][6] + bvv[6], acc[i][7] + bvv[7]);
            *(float4*)(v + (size_t)n * 128 + c0)     = o0;
            *(float4*)(v + (size_t)n * 128 + c0 + 4) = o1;
        }
    }
}

// ---------------------------------------------------------------------------
// edge: one thread per edge. logits[e][h] = MLP(edge_attr) - dist2/(2 sigma^2)
// Weights broadcast from LDS (4x ds_read_b128 per hidden unit).
// ---------------------------------------------------------------------------
__global__ __launch_bounds__(256) void edge_kernel(const float* __restrict__ pos_obs,
                                                   const float* __restrict__ pos_query,
                                                   const int* __restrict__ src,
                                                   const int* __restrict__ dst,
                                                   const float* __restrict__ pack,
                                                   float4* __restrict__ logits) {
    __shared__ float4 sh[514];
    int t = threadIdx.x;
    for (int idx = t; idx < 514; idx += 256) sh[idx] = ((const float4*)pack)[idx];
    __syncthreads();

    int e = blockIdx.x * 256 + t;
    if (e >= NE) return;
    int s = src[e], d = dst[e];
    float pox = pos_obs[s * 3 + 0], poy = pos_obs[s * 3 + 1], poz = pos_obs[s * 3 + 2];
    float pqx = pos_query[d * 3 + 0], pqy = pos_query[d * 3 + 1], pqz = pos_query[d * 3 + 2];
    float rx = pqx - pox, ry = pqy - poy, rz = pqz - poz;
    float ea0 = rx, ea1 = ry, ea2 = rz, ea3 = pqx, ea4 = pqy, ea5 = pqz,
          ea6 = pox, ea7 = poy, ea8 = poz;
    float dist2 = rx * rx + ry * ry + rz * rz;

    float4 ex = sh[512];            // [inv2s2, b2_0, b2_1, b2_2]
    float b23 = sh[513].x;          // b2_3
    float pen = dist2 * ex.x;
    float a0 = ex.y - pen, a1 = ex.z - pen, a2 = ex.w - pen, a3 = b23 - pen;

    #pragma unroll 4
    for (int j = 0; j < 128; ++j) {
        float4 wa = sh[j * 4 + 0];
        float4 wb = sh[j * 4 + 1];
        float4 wc = sh[j * 4 + 2];  // [W1_8, b1, W2_0, W2_1]
        float4 wd = sh[j * 4 + 3];  // [W2_2, W2_3, -, -]
        float hsum = wc.y + ea0 * wa.x + ea1 * wa.y + ea2 * wa.z + ea3 * wa.w
                           + ea4 * wb.x + ea5 * wb.y + ea6 * wb.z + ea7 * wb.w
                           + ea8 * wc.x;
        hsum = fmaxf(hsum, 0.f);
        a0 += hsum * wc.z; a1 += hsum * wc.w;
        a2 += hsum * wd.x; a3 += hsum * wd.y;
    }
    logits[e] = make_float4(a0, a1, a2, a3);
}

// ---------------------------------------------------------------------------
// attn: one wave per query (4 queries / 256-thread block). Shuffle-only
// segment softmax (lanes = 4 heads x 16), then each lane accumulates 2
// output channels over the query's edges with coalesced v-row gathers.
// ---------------------------------------------------------------------------
__global__ __launch_bounds__(256) void attn_kernel(const float* __restrict__ v,
                                                   const float* __restrict__ logitsf,
                                                   const int* __restrict__ src,
                                                   const int* __restrict__ rp,
                                                   float* __restrict__ out) {
    int t = threadIdx.x;
    int lane = t & 63;
    int q = blockIdx.x * 4 + (t >> 6);
    int s0 = rp[q], s1 = rp[q + 1];
    int h = lane >> 4, i = lane & 15;

    float m = -INFINITY;
    for (int e = s0 + i; e < s1; e += 16) m = fmaxf(m, logitsf[e * 4 + h]);
    #pragma unroll
    for (int off = 8; off; off >>= 1) m = fmaxf(m, __shfl_xor(m, off));

    float sum = 0.f;
    for (int e = s0 + i; e < s1; e += 16) sum += expf(logitsf[e * 4 + h] - m);
    #pragma unroll
    for (int off = 8; off; off >>= 1) sum += __shfl_xor(sum, off);
    float r = 1.0f / (sum + 1e-16f);

    // phase B: lane owns channels d0, d0+1; note (lane*2)>>5 == lane>>4 == h
    int d0 = lane * 2;
    float acc0 = 0.f, acc1 = 0.f;
    for (int e = s0; e < s1; ++e) {
        float l = logitsf[e * 4 + h];
        float w = expf(l - m) * r;
        const float* vr = v + (size_t)src[e] * 128 + d0;
        acc0 += w * vr[0];
        acc1 += w * vr[1];
    }
    *(float2*)(out + (size_t)q * 128 + d0) = make_float2(acc0, acc1);
}

// ---------------------------------------------------------------------------
extern "C" void kernel_launch(void* const* d_in, const int* in_sizes, int n_in,
                              void* d_out, int out_size, void* d_ws, size_t ws_size,
                              hipStream_t stream) {
    const float* h_obs     = (const float*)d_in[0];
    const float* pos_obs   = (const float*)d_in[1];
    const float* pos_query = (const float*)d_in[2];
    const int*   src       = (const int*)d_in[3];
    const int*   dst       = (const int*)d_in[4];
    const float* W1        = (const float*)d_in[5];
    const float* b1        = (const float*)d_in[6];
    const float* W2        = (const float*)d_in[7];
    const float* b2        = (const float*)d_in[8];
    const float* Wv        = (const float*)d_in[9];
    const float* bv        = (const float*)d_in[10];
    const float* log_sigma = (const float*)d_in[11];
    float* out = (float*)d_out;

    char* ws = (char*)d_ws;
    int*   rp    = (int*)(ws + 0);                 // 50001 ints  (end 200004)
    float* pack  = (float*)(ws + 200192);          // 2056 floats (end 208416)
    float* vbuf  = (float*)(ws + 208640);          // 6.4M floats (end 25808640)
    float* logits= (float*)(ws + 25808640);        // 6.4M floats (end 51408640)

    hipLaunchKernelGGL(pack_kernel, dim3(1), dim3(256), 0, stream,
                       W1, b1, W2, b2, log_sigma, pack);
    hipLaunchKernelGGL(rowptr_kernel, dim3((N_Q + 256) / 256), dim3(256), 0, stream,
                       dst, rp);
    hipLaunchKernelGGL(vproj_kernel, dim3((N_O + 63) / 64), dim3(256), 0, stream,
                       h_obs, Wv, bv, vbuf);
    hipLaunchKernelGGL(edge_kernel, dim3((NE + 255) / 256), dim3(256), 0, stream,
                       pos_obs, pos_query, src, dst, pack, (float4*)logits);
    hipLaunchKernelGGL(attn_kernel, dim3(N_Q / 4), dim3(256), 0, stream,
                       vbuf, logits, src, rp, out);
}

// Round 2
// 356.089 us; speedup vs baseline: 1.3697x; 1.3697x over previous
//
#include <hip/hip_runtime.h>
#include <hip/hip_bf16.h>
#include <cstdint>
#include <cstddef>

#define N_O 50000
#define N_Q 50000
#define NE  1600000
// LATENT=128, HEADS=4, HEAD_DIM=32

// ---------------------------------------------------------------------------
// pack: per-j 16-float struct for the edge MLP:
//  [0..3]=W1[0..3][j] [4..7]=W1[4..7][j] [8]=W1[8][j] [9]=b1[j]
//  [10..13]=W2[j][0..3] [14..15]=pad
// extras at float offset 2048: [0]=1/(2*sigma^2), [1..4]=b2[0..3]
// ---------------------------------------------------------------------------
__global__ void pack_kernel(const float* __restrict__ W1, const float* __restrict__ b1,
                            const float* __restrict__ W2, const float* __restrict__ b2,
                            const float* __restrict__ log_sigma, float* __restrict__ pack) {
    int j = threadIdx.x;
    if (j < 128) {
        float* p = pack + j * 16;
        #pragma unroll
        for (int i = 0; i < 9; ++i) p[i] = W1[i * 128 + j];
        p[9]  = b1[j];
        p[10] = W2[j * 4 + 0]; p[11] = W2[j * 4 + 1];
        p[12] = W2[j * 4 + 2]; p[13] = W2[j * 4 + 3];
        p[14] = 0.f; p[15] = 0.f;
    } else if (j == 128) {
        float sigma = expf(log_sigma[0]) + 1e-6f;
        pack[2048] = 1.0f / (2.0f * sigma * sigma);
        pack[2049] = b2[0]; pack[2050] = b2[1];
        pack[2051] = b2[2]; pack[2052] = b2[3];
        pack[2053] = 0.f; pack[2054] = 0.f; pack[2055] = 0.f;
    }
}

// ---------------------------------------------------------------------------
// rowptr: rp[q] = lower_bound(dst, q) for q in [0, N_Q]  (dst is sorted)
// ---------------------------------------------------------------------------
__global__ void rowptr_kernel(const int* __restrict__ dst, int* __restrict__ rp) {
    int q = blockIdx.x * blockDim.x + threadIdx.x;
    if (q > N_Q) return;
    int lo = 0, hi = NE;
    while (lo < hi) {
        int mid = (lo + hi) >> 1;
        if (dst[mid] < q) lo = mid + 1; else hi = mid;
    }
    rp[q] = lo;
}

// ---------------------------------------------------------------------------
// vproj: v = h_obs @ Wv + bv   [50000,128] = [50000,128]@[128,128]
// fp32 compute, bf16 output (halves attn gather traffic).
// 64 rows per block, 256 threads, 4x8 outputs per thread.
// ---------------------------------------------------------------------------
__global__ __launch_bounds__(256) void vproj_kernel(const float* __restrict__ h,
                                                    const float* __restrict__ Wv,
                                                    const float* __restrict__ bv,
                                                    unsigned short* __restrict__ v) {
    __shared__ float Ash[64 * 132];
    int t = threadIdx.x;
    int n0 = blockIdx.x * 64;
    #pragma unroll
    for (int rep = 0; rep < 8; ++rep) {
        int idx = rep * 256 + t;           // flat over [64][32] float4s
        int row = idx >> 5, c4 = (idx & 31) * 4;
        float4 val = make_float4(0.f, 0.f, 0.f, 0.f);
        if (n0 + row < N_O) val = *(const float4*)(h + (size_t)(n0 + row) * 128 + c4);
        float* d = &Ash[row * 132 + c4];
        d[0] = val.x; d[1] = val.y; d[2] = val.z; d[3] = val.w;
    }
    __syncthreads();

    int cg = t & 15, rg = t >> 4;
    int c0 = cg * 8, r0 = rg * 4;
    float acc[4][8];
    #pragma unroll
    for (int i = 0; i < 4; ++i)
        #pragma unroll
        for (int j = 0; j < 8; ++j) acc[i][j] = 0.f;

    const float4* Wv4 = (const float4*)Wv;
    for (int k = 0; k < 128; ++k) {
        float4 b0 = Wv4[k * 32 + cg * 2];
        float4 b1v = Wv4[k * 32 + cg * 2 + 1];
        float bb[8] = {b0.x, b0.y, b0.z, b0.w, b1v.x, b1v.y, b1v.z, b1v.w};
        #pragma unroll
        for (int i = 0; i < 4; ++i) {
            float a = Ash[(r0 + i) * 132 + k];
            #pragma unroll
            for (int j = 0; j < 8; ++j) acc[i][j] += a * bb[j];
        }
    }

    float bvv[8];
    #pragma unroll
    for (int j = 0; j < 8; ++j) bvv[j] = bv[c0 + j];
    #pragma unroll
    for (int i = 0; i < 4; ++i) {
        int n = n0 + r0 + i;
        if (n < N_O) {
            uint4 o;
            {
                __hip_bfloat162 t0 = __float22bfloat162_rn(
                    make_float2(acc[i][0] + bvv[0], acc[i][1] + bvv[1]));
                __hip_bfloat162 t1 = __float22bfloat162_rn(
                    make_float2(acc[i][2] + bvv[2], acc[i][3] + bvv[3]));
                __hip_bfloat162 t2 = __float22bfloat162_rn(
                    make_float2(acc[i][4] + bvv[4], acc[i][5] + bvv[5]));
                __hip_bfloat162 t3 = __float22bfloat162_rn(
                    make_float2(acc[i][6] + bvv[6], acc[i][7] + bvv[7]));
                o.x = *reinterpret_cast<unsigned int*>(&t0);
                o.y = *reinterpret_cast<unsigned int*>(&t1);
                o.z = *reinterpret_cast<unsigned int*>(&t2);
                o.w = *reinterpret_cast<unsigned int*>(&t3);
            }
            *(uint4*)(v + (size_t)n * 128 + c0) = o;   // 16 B aligned (c0 % 8 == 0)
        }
    }
}

// ---------------------------------------------------------------------------
// edge: 4 consecutive edges per thread. Each ds_read_b128 of weights now
// feeds 4 edges' FMAs -> VALU-bound instead of LDS-issue-bound.
// ---------------------------------------------------------------------------
__global__ __launch_bounds__(256) void edge_kernel(const float* __restrict__ pos_obs,
                                                   const float* __restrict__ pos_query,
                                                   const int* __restrict__ src,
                                                   const int* __restrict__ dst,
                                                   const float* __restrict__ pack,
                                                   float4* __restrict__ logits) {
    __shared__ float4 sh[514];
    int t = threadIdx.x;
    for (int idx = t; idx < 514; idx += 256) sh[idx] = ((const float4*)pack)[idx];
    __syncthreads();

    int base = (blockIdx.x * 256 + t) * 4;
    if (base >= NE) return;                       // NE % 4 == 0, so all-or-nothing
    int4 s4 = *(const int4*)(src + base);
    int4 d4 = *(const int4*)(dst + base);
    int ss[4] = {s4.x, s4.y, s4.z, s4.w};
    int dd[4] = {d4.x, d4.y, d4.z, d4.w};

    float ea[4][9];
    float a[4][4];
    float4 ex = sh[512];            // [inv2s2, b2_0, b2_1, b2_2]
    float b23 = sh[513].x;          // b2_3
    #pragma unroll
    for (int u = 0; u < 4; ++u) {
        float pox = pos_obs[ss[u] * 3 + 0], poy = pos_obs[ss[u] * 3 + 1],
              poz = pos_obs[ss[u] * 3 + 2];
        float pqx = pos_query[dd[u] * 3 + 0], pqy = pos_query[dd[u] * 3 + 1],
              pqz = pos_query[dd[u] * 3 + 2];
        float rx = pqx - pox, ry = pqy - poy, rz = pqz - poz;
        ea[u][0] = rx;  ea[u][1] = ry;  ea[u][2] = rz;
        ea[u][3] = pqx; ea[u][4] = pqy; ea[u][5] = pqz;
        ea[u][6] = pox; ea[u][7] = poy; ea[u][8] = poz;
        float dist2 = rx * rx + ry * ry + rz * rz;
        float pen = dist2 * ex.x;
        a[u][0] = ex.y - pen; a[u][1] = ex.z - pen;
        a[u][2] = ex.w - pen; a[u][3] = b23 - pen;
    }

    #pragma unroll 2
    for (int j = 0; j < 128; ++j) {
        float4 wa = sh[j * 4 + 0];
        float4 wb = sh[j * 4 + 1];
        float4 wc = sh[j * 4 + 2];  // [W1_8, b1, W2_0, W2_1]
        float4 wd = sh[j * 4 + 3];  // [W2_2, W2_3, -, -]
        #pragma unroll
        for (int u = 0; u < 4; ++u) {
            float hsum = wc.y + ea[u][0] * wa.x + ea[u][1] * wa.y + ea[u][2] * wa.z
                              + ea[u][3] * wa.w + ea[u][4] * wb.x + ea[u][5] * wb.y
                              + ea[u][6] * wb.z + ea[u][7] * wb.w + ea[u][8] * wc.x;
            hsum = fmaxf(hsum, 0.f);
            a[u][0] += hsum * wc.z; a[u][1] += hsum * wc.w;
            a[u][2] += hsum * wd.x; a[u][3] += hsum * wd.y;
        }
    }
    #pragma unroll
    for (int u = 0; u < 4; ++u)
        logits[base + u] = make_float4(a[u][0], a[u][1], a[u][2], a[u][3]);
}

// ---------------------------------------------------------------------------
// attn: one wave per query (4 queries / 256-thread block). Shuffle-only
// segment softmax (lanes = 4 heads x 16), then each lane accumulates 2
// output channels over the query's edges; v gathered as bf16 (4 B/lane).
// ---------------------------------------------------------------------------
__global__ __launch_bounds__(256) void attn_kernel(const __hip_bfloat162* __restrict__ vb,
                                                   const float* __restrict__ logitsf,
                                                   const int* __restrict__ src,
                                                   const int* __restrict__ rp,
                                                   float* __restrict__ out) {
    int t = threadIdx.x;
    int lane = t & 63;
    int q = blockIdx.x * 4 + (t >> 6);
    int s0 = rp[q], s1 = rp[q + 1];
    int h = lane >> 4, i = lane & 15;

    float m = -INFINITY;
    for (int e = s0 + i; e < s1; e += 16) m = fmaxf(m, logitsf[e * 4 + h]);
    #pragma unroll
    for (int off = 8; off; off >>= 1) m = fmaxf(m, __shfl_xor(m, off));

    float sum = 0.f;
    for (int e = s0 + i; e < s1; e += 16) sum += expf(logitsf[e * 4 + h] - m);
    #pragma unroll
    for (int off = 8; off; off >>= 1) sum += __shfl_xor(sum, off);
    float r = 1.0f / (sum + 1e-16f);

    // phase B: lane owns channels 2*lane, 2*lane+1; (lane*2)>>5 == lane>>4 == h
    float acc0 = 0.f, acc1 = 0.f;
    int e = s0;
    for (; e + 1 < s1; e += 2) {
        float l0 = logitsf[e * 4 + h];
        float l1 = logitsf[(e + 1) * 4 + h];
        int sA = src[e], sB = src[e + 1];
        __hip_bfloat162 vA = vb[(size_t)sA * 64 + lane];
        __hip_bfloat162 vB = vb[(size_t)sB * 64 + lane];
        float wA = expf(l0 - m) * r;
        float wB = expf(l1 - m) * r;
        float2 fA = __bfloat1622float2(vA);
        float2 fB = __bfloat1622float2(vB);
        acc0 += wA * fA.x + wB * fB.x;
        acc1 += wA * fA.y + wB * fB.y;
    }
    if (e < s1) {
        float l = logitsf[e * 4 + h];
        float w = expf(l - m) * r;
        float2 f = __bfloat1622float2(vb[(size_t)src[e] * 64 + lane]);
        acc0 += w * f.x;
        acc1 += w * f.y;
    }
    *(float2*)(out + (size_t)q * 128 + lane * 2) = make_float2(acc0, acc1);
}

// ---------------------------------------------------------------------------
extern "C" void kernel_launch(void* const* d_in, const int* in_sizes, int n_in,
                              void* d_out, int out_size, void* d_ws, size_t ws_size,
                              hipStream_t stream) {
    const float* h_obs     = (const float*)d_in[0];
    const float* pos_obs   = (const float*)d_in[1];
    const float* pos_query = (const float*)d_in[2];
    const int*   src       = (const int*)d_in[3];
    const int*   dst       = (const int*)d_in[4];
    const float* W1        = (const float*)d_in[5];
    const float* b1        = (const float*)d_in[6];
    const float* W2        = (const float*)d_in[7];
    const float* b2        = (const float*)d_in[8];
    const float* Wv        = (const float*)d_in[9];
    const float* bv        = (const float*)d_in[10];
    const float* log_sigma = (const float*)d_in[11];
    float* out = (float*)d_out;

    char* ws = (char*)d_ws;
    int*            rp     = (int*)(ws + 0);          // 50001 ints (end 200004)
    float*          pack   = (float*)(ws + 200192);   // 2056 floats (end 208416)
    unsigned short* vbuf   = (unsigned short*)(ws + 208640);   // 6.4M bf16 (end 13,008,640)
    float*          logits = (float*)(ws + 13008768); // 6.4M floats (end 38,608,768)

    hipLaunchKernelGGL(pack_kernel, dim3(1), dim3(256), 0, stream,
                       W1, b1, W2, b2, log_sigma, pack);
    hipLaunchKernelGGL(rowptr_kernel, dim3((N_Q + 256) / 256), dim3(256), 0, stream,
                       dst, rp);
    hipLaunchKernelGGL(vproj_kernel, dim3((N_O + 63) / 64), dim3(256), 0, stream,
                       h_obs, Wv, bv, vbuf);
    hipLaunchKernelGGL(edge_kernel, dim3((NE / 4 + 255) / 256), dim3(256), 0, stream,
                       pos_obs, pos_query, src, dst, pack, (float4*)logits);
    hipLaunchKernelGGL(attn_kernel, dim3(N_Q / 4), dim3(256), 0, stream,
                       (const __hip_bfloat162*)vbuf, logits, src, rp, out);
}

// Round 3
// 283.929 us; speedup vs baseline: 1.7178x; 1.2541x over previous
//
#include <hip/hip_runtime.h>
#include <hip/hip_bf16.h>
#include <cstdint>
#include <cstddef>

#define N_O 50000
#define N_Q 50000
#define NE  1600000
// LATENT=128, HEADS=4, HEAD_DIM=32

typedef __attribute__((ext_vector_type(8)))  short short8;
typedef __attribute__((ext_vector_type(16))) float f32x16;

__device__ inline unsigned short f2bf(float x) {
    __hip_bfloat16 hb = __float2bfloat16(x);
    return *reinterpret_cast<unsigned short*>(&hb);
}

// ---------------------------------------------------------------------------
// pack: build bf16 weight tensors for the MFMA edge MLP.
//  W1cT [128 hidden][8 attr] bf16 : attrs = [Wq+Wr (3), Wo-Wr (3), b1, 0]
//  W2tb [4 head][128 hidden] bf16
//  scal fp32: [0]=1/(2 sigma^2), [1..4]=b2
// ---------------------------------------------------------------------------
__global__ void pack_kernel(const float* __restrict__ W1, const float* __restrict__ b1,
                            const float* __restrict__ W2, const float* __restrict__ b2,
                            const float* __restrict__ log_sigma,
                            unsigned short* __restrict__ W1cT,
                            unsigned short* __restrict__ W2tb,
                            float* __restrict__ scal) {
    int j = threadIdx.x;
    if (j < 128) {
        #pragma unroll
        for (int a = 0; a < 3; ++a) {
            W1cT[j * 8 + a]     = f2bf(W1[(3 + a) * 128 + j] + W1[a * 128 + j]); // pq coef
            W1cT[j * 8 + 3 + a] = f2bf(W1[(6 + a) * 128 + j] - W1[a * 128 + j]); // po coef
        }
        W1cT[j * 8 + 6] = f2bf(b1[j]);
        W1cT[j * 8 + 7] = 0;
        #pragma unroll
        for (int hd = 0; hd < 4; ++hd)
            W2tb[hd * 128 + j] = f2bf(W2[j * 4 + hd]);
    } else if (j == 128) {
        float sigma = expf(log_sigma[0]) + 1e-6f;
        scal[0] = 1.0f / (2.0f * sigma * sigma);
        scal[1] = b2[0]; scal[2] = b2[1]; scal[3] = b2[2]; scal[4] = b2[3];
    }
}

// ---------------------------------------------------------------------------
// rowptr: rp[q] = lower_bound(dst, q) for q in [0, N_Q]  (dst is sorted)
// ---------------------------------------------------------------------------
__global__ void rowptr_kernel(const int* __restrict__ dst, int* __restrict__ rp) {
    int q = blockIdx.x * blockDim.x + threadIdx.x;
    if (q > N_Q) return;
    int lo = 0, hi = NE;
    while (lo < hi) {
        int mid = (lo + hi) >> 1;
        if (dst[mid] < q) lo = mid + 1; else hi = mid;
    }
    rp[q] = lo;
}

// ---------------------------------------------------------------------------
// vproj: v = h_obs @ Wv + bv, fp32 compute, bf16 output.
// ---------------------------------------------------------------------------
__global__ __launch_bounds__(256) void vproj_kernel(const float* __restrict__ h,
                                                    const float* __restrict__ Wv,
                                                    const float* __restrict__ bv,
                                                    unsigned short* __restrict__ v) {
    __shared__ float Ash[64 * 132];
    int t = threadIdx.x;
    int n0 = blockIdx.x * 64;
    #pragma unroll
    for (int rep = 0; rep < 8; ++rep) {
        int idx = rep * 256 + t;
        int row = idx >> 5, c4 = (idx & 31) * 4;
        float4 val = make_float4(0.f, 0.f, 0.f, 0.f);
        if (n0 + row < N_O) val = *(const float4*)(h + (size_t)(n0 + row) * 128 + c4);
        float* d = &Ash[row * 132 + c4];
        d[0] = val.x; d[1] = val.y; d[2] = val.z; d[3] = val.w;
    }
    __syncthreads();

    int cg = t & 15, rg = t >> 4;
    int c0 = cg * 8, r0 = rg * 4;
    float acc[4][8];
    #pragma unroll
    for (int i = 0; i < 4; ++i)
        #pragma unroll
        for (int j = 0; j < 8; ++j) acc[i][j] = 0.f;

    const float4* Wv4 = (const float4*)Wv;
    for (int k = 0; k < 128; ++k) {
        float4 b0 = Wv4[k * 32 + cg * 2];
        float4 b1v = Wv4[k * 32 + cg * 2 + 1];
        float bb[8] = {b0.x, b0.y, b0.z, b0.w, b1v.x, b1v.y, b1v.z, b1v.w};
        #pragma unroll
        for (int i = 0; i < 4; ++i) {
            float a = Ash[(r0 + i) * 132 + k];
            #pragma unroll
            for (int j = 0; j < 8; ++j) acc[i][j] += a * bb[j];
        }
    }

    float bvv[8];
    #pragma unroll
    for (int j = 0; j < 8; ++j) bvv[j] = bv[c0 + j];
    #pragma unroll
    for (int i = 0; i < 4; ++i) {
        int n = n0 + r0 + i;
        if (n < N_O) {
            uint4 o;
            __hip_bfloat162 t0 = __float22bfloat162_rn(
                make_float2(acc[i][0] + bvv[0], acc[i][1] + bvv[1]));
            __hip_bfloat162 t1 = __float22bfloat162_rn(
                make_float2(acc[i][2] + bvv[2], acc[i][3] + bvv[3]));
            __hip_bfloat162 t2 = __float22bfloat162_rn(
                make_float2(acc[i][4] + bvv[4], acc[i][5] + bvv[5]));
            __hip_bfloat162 t3 = __float22bfloat162_rn(
                make_float2(acc[i][6] + bvv[6], acc[i][7] + bvv[7]));
            o.x = *reinterpret_cast<unsigned int*>(&t0);
            o.y = *reinterpret_cast<unsigned int*>(&t1);
            o.z = *reinterpret_cast<unsigned int*>(&t2);
            o.w = *reinterpret_cast<unsigned int*>(&t3);
            *(uint4*)(v + (size_t)n * 128 + c0) = o;
        }
    }
}

// ---------------------------------------------------------------------------
// edge (MFMA): one wave = 32 edges.
//  GEMM1: C1[hidden 128][edge 32] = W1cT(A) @ ea^T(B), 4x mfma_32x32x16_bf16
//         A: lane(h=0) holds W1cT[32b+i][0..7]; h=1 lanes zero (K pad).
//         B: lane(h=0) holds attrs [pq,po,1,0] bf16 of edge i; h=1 zero.
//  relu -> bf16 -> LDS tile [edge][hidden], row stride 264 B.
//  GEMM2: C2[head][edge] = W2tb(A) @ hid(B), 8x mfma, K=128.
//         B: lane reads hid[edge=i][16m+8h .. +7] via 2x ds_read_b64.
//  Output: h=0 lanes hold heads 0..3 in regs 0..3 -> float4 store + fp32
//          dist2 penalty + b2.
// ---------------------------------------------------------------------------
__global__ __launch_bounds__(256) void edge_kernel(const float* __restrict__ pos_obs,
                                                   const float* __restrict__ pos_query,
                                                   const int* __restrict__ src,
                                                   const int* __restrict__ dst,
                                                   const unsigned short* __restrict__ W1cT,
                                                   const unsigned short* __restrict__ W2tb,
                                                   const float* __restrict__ scal,
                                                   float4* __restrict__ logits) {
    __shared__ __align__(16) unsigned char smem[4 * 8448];
    int t = threadIdx.x;
    int wave = t >> 6, lane = t & 63;
    int i = lane & 31, h = lane >> 5;
    unsigned char* myrow = smem + wave * 8448 + i * 264;

    // A-fragments (persistent)
    short8 zero8;
    #pragma unroll
    for (int k = 0; k < 8; ++k) zero8[k] = 0;

    short8 a1[4];
    #pragma unroll
    for (int b = 0; b < 4; ++b)
        a1[b] = (h == 0) ? *(const short8*)(W1cT + (32 * b + i) * 8) : zero8;

    short8 a2[8];
    #pragma unroll
    for (int m = 0; m < 8; ++m)
        a2[m] = (i < 4) ? *(const short8*)(W2tb + i * 128 + m * 16 + h * 8) : zero8;

    // stage this lane's edge
    int e = blockIdx.x * 128 + wave * 32 + i;
    int s = src[e], d = dst[e];
    float pox = pos_obs[s * 3 + 0], poy = pos_obs[s * 3 + 1], poz = pos_obs[s * 3 + 2];
    float pqx = pos_query[d * 3 + 0], pqy = pos_query[d * 3 + 1], pqz = pos_query[d * 3 + 2];
    float rx = pqx - pox, ry = pqy - poy, rz = pqz - poz;
    float dist2 = rx * rx + ry * ry + rz * rz;

    short8 bea = zero8;
    if (h == 0) {
        bea[0] = (short)f2bf(pqx); bea[1] = (short)f2bf(pqy); bea[2] = (short)f2bf(pqz);
        bea[3] = (short)f2bf(pox); bea[4] = (short)f2bf(poy); bea[5] = (short)f2bf(poz);
        bea[6] = (short)0x3F80;    // 1.0 bf16 (bias attr)
        bea[7] = 0;
    }

    // GEMM1
    f32x16 c1[4];
    #pragma unroll
    for (int b = 0; b < 4; ++b) {
        #pragma unroll
        for (int k = 0; k < 16; ++k) c1[b][k] = 0.0f;
        c1[b] = __builtin_amdgcn_mfma_f32_32x32x16_bf16(a1[b], bea, c1[b], 0, 0, 0);
    }

    // relu -> bf16 -> LDS  (reg r+4s -> hidden 32b + 8s + 4h + r)
    #pragma unroll
    for (int b = 0; b < 4; ++b) {
        #pragma unroll
        for (int s_ = 0; s_ < 4; ++s_) {
            float x0 = fmaxf(c1[b][4 * s_ + 0], 0.f);
            float x1 = fmaxf(c1[b][4 * s_ + 1], 0.f);
            float x2 = fmaxf(c1[b][4 * s_ + 2], 0.f);
            float x3 = fmaxf(c1[b][4 * s_ + 3], 0.f);
            __hip_bfloat162 p0 = __float22bfloat162_rn(make_float2(x0, x1));
            __hip_bfloat162 p1 = __float22bfloat162_rn(make_float2(x2, x3));
            uint2 w;
            w.x = *reinterpret_cast<unsigned int*>(&p0);
            w.y = *reinterpret_cast<unsigned int*>(&p1);
            *(uint2*)(myrow + 64 * b + 16 * s_ + 8 * h) = w;
        }
    }
    // same-wave LDS RAW: compiler inserts lgkmcnt wait; no cross-wave sharing.

    // GEMM2
    f32x16 c2;
    #pragma unroll
    for (int k = 0; k < 16; ++k) c2[k] = 0.0f;
    #pragma unroll
    for (int m = 0; m < 8; ++m) {
        uint2 lo = *(const uint2*)(myrow + 32 * m + 16 * h);
        uint2 hi = *(const uint2*)(myrow + 32 * m + 16 * h + 8);
        union { unsigned int u[4]; short8 s; } bf;
        bf.u[0] = lo.x; bf.u[1] = lo.y; bf.u[2] = hi.x; bf.u[3] = hi.y;
        c2 = __builtin_amdgcn_mfma_f32_32x32x16_bf16(a2[m], bf.s, c2, 0, 0, 0);
    }

    if (h == 0) {
        float pen = dist2 * scal[0];
        float4 o;
        o.x = c2[0] + scal[1] - pen;
        o.y = c2[1] + scal[2] - pen;
        o.z = c2[2] + scal[3] - pen;
        o.w = c2[3] + scal[4] - pen;
        logits[e] = o;
    }
}

// ---------------------------------------------------------------------------
// attn: one wave per query. Shuffle-only segment softmax, bf16 v gathers.
// ---------------------------------------------------------------------------
__global__ __launch_bounds__(256) void attn_kernel(const __hip_bfloat162* __restrict__ vb,
                                                   const float* __restrict__ logitsf,
                                                   const int* __restrict__ src,
                                                   const int* __restrict__ rp,
                                                   float* __restrict__ out) {
    int t = threadIdx.x;
    int lane = t & 63;
    int q = blockIdx.x * 4 + (t >> 6);
    int s0 = rp[q], s1 = rp[q + 1];
    int h = lane >> 4, i = lane & 15;

    float m = -INFINITY;
    for (int e = s0 + i; e < s1; e += 16) m = fmaxf(m, logitsf[e * 4 + h]);
    #pragma unroll
    for (int off = 8; off; off >>= 1) m = fmaxf(m, __shfl_xor(m, off));

    float sum = 0.f;
    for (int e = s0 + i; e < s1; e += 16) sum += expf(logitsf[e * 4 + h] - m);
    #pragma unroll
    for (int off = 8; off; off >>= 1) sum += __shfl_xor(sum, off);
    float r = 1.0f / (sum + 1e-16f);

    float acc0 = 0.f, acc1 = 0.f;
    int e = s0;
    for (; e + 1 < s1; e += 2) {
        float l0 = logitsf[e * 4 + h];
        float l1 = logitsf[(e + 1) * 4 + h];
        int sA = src[e], sB = src[e + 1];
        __hip_bfloat162 vA = vb[(size_t)sA * 64 + lane];
        __hip_bfloat162 vB = vb[(size_t)sB * 64 + lane];
        float wA = expf(l0 - m) * r;
        float wB = expf(l1 - m) * r;
        float2 fA = __bfloat1622float2(vA);
        float2 fB = __bfloat1622float2(vB);
        acc0 += wA * fA.x + wB * fB.x;
        acc1 += wA * fA.y + wB * fB.y;
    }
    if (e < s1) {
        float l = logitsf[e * 4 + h];
        float w = expf(l - m) * r;
        float2 f = __bfloat1622float2(vb[(size_t)src[e] * 64 + lane]);
        acc0 += w * f.x;
        acc1 += w * f.y;
    }
    *(float2*)(out + (size_t)q * 128 + lane * 2) = make_float2(acc0, acc1);
}

// ---------------------------------------------------------------------------
extern "C" void kernel_launch(void* const* d_in, const int* in_sizes, int n_in,
                              void* d_out, int out_size, void* d_ws, size_t ws_size,
                              hipStream_t stream) {
    const float* h_obs     = (const float*)d_in[0];
    const float* pos_obs   = (const float*)d_in[1];
    const float* pos_query = (const float*)d_in[2];
    const int*   src       = (const int*)d_in[3];
    const int*   dst       = (const int*)d_in[4];
    const float* W1        = (const float*)d_in[5];
    const float* b1        = (const float*)d_in[6];
    const float* W2        = (const float*)d_in[7];
    const float* b2        = (const float*)d_in[8];
    const float* Wv        = (const float*)d_in[9];
    const float* bv        = (const float*)d_in[10];
    const float* log_sigma = (const float*)d_in[11];
    float* out = (float*)d_out;

    char* ws = (char*)d_ws;
    int*            rp     = (int*)(ws + 0);                   // 50001 ints  (end 200004)
    float*          scal   = (float*)(ws + 200192);            // 8 floats    (end 200224)
    unsigned short* W1cT   = (unsigned short*)(ws + 200256);   // 1024 bf16   (end 202304)
    unsigned short* W2tb   = (unsigned short*)(ws + 202304);   // 512 bf16    (end 203328)
    unsigned short* vbuf   = (unsigned short*)(ws + 208640);   // 6.4M bf16   (end 13,008,640)
    float*          logits = (float*)(ws + 13008768);          // 6.4M floats (end 38,608,768)

    hipLaunchKernelGGL(pack_kernel, dim3(1), dim3(256), 0, stream,
                       W1, b1, W2, b2, log_sigma, W1cT, W2tb, scal);
    hipLaunchKernelGGL(rowptr_kernel, dim3((N_Q + 256) / 256), dim3(256), 0, stream,
                       dst, rp);
    hipLaunchKernelGGL(vproj_kernel, dim3((N_O + 63) / 64), dim3(256), 0, stream,
                       h_obs, Wv, bv, vbuf);
    hipLaunchKernelGGL(edge_kernel, dim3(NE / 128), dim3(256), 0, stream,
                       pos_obs, pos_query, src, dst, W1cT, W2tb, scal, (float4*)logits);
    hipLaunchKernelGGL(attn_kernel, dim3(N_Q / 4), dim3(256), 0, stream,
                       (const __hip_bfloat162*)vbuf, logits, src, rp, out);
}

// Round 4
// 257.429 us; speedup vs baseline: 1.8946x; 1.1029x over previous
//
#include <hip/hip_runtime.h>
#include <hip/hip_bf16.h>
#include <cstdint>
#include <cstddef>

#define N_O 50000
#define N_Q 50000
#define NE  1600000
// LATENT=128, HEADS=4, HEAD_DIM=32

typedef __attribute__((ext_vector_type(8)))  short short8;
typedef __attribute__((ext_vector_type(16))) float f32x16;

__device__ inline unsigned short f2bf(float x) {
    __hip_bfloat16 hb = __float2bfloat16(x);
    return *reinterpret_cast<unsigned short*>(&hb);
}

// ---------------------------------------------------------------------------
// pack: build bf16 weight tensors for the MFMA edge MLP.
//  W1cT [128 hidden][8 attr] bf16 : attrs = [Wq+Wr (3), Wo-Wr (3), b1, 0]
//  W2tb [4 head][128 hidden] bf16
//  scal fp32: [0]=1/(2 sigma^2), [1..4]=b2
// ---------------------------------------------------------------------------
__global__ void pack_kernel(const float* __restrict__ W1, const float* __restrict__ b1,
                            const float* __restrict__ W2, const float* __restrict__ b2,
                            const float* __restrict__ log_sigma,
                            unsigned short* __restrict__ W1cT,
                            unsigned short* __restrict__ W2tb,
                            float* __restrict__ scal) {
    int j = threadIdx.x;
    if (j < 128) {
        #pragma unroll
        for (int a = 0; a < 3; ++a) {
            W1cT[j * 8 + a]     = f2bf(W1[(3 + a) * 128 + j] + W1[a * 128 + j]); // pq coef
            W1cT[j * 8 + 3 + a] = f2bf(W1[(6 + a) * 128 + j] - W1[a * 128 + j]); // po coef
        }
        W1cT[j * 8 + 6] = f2bf(b1[j]);
        W1cT[j * 8 + 7] = 0;
        #pragma unroll
        for (int hd = 0; hd < 4; ++hd)
            W2tb[hd * 128 + j] = f2bf(W2[j * 4 + hd]);
    } else if (j == 128) {
        float sigma = expf(log_sigma[0]) + 1e-6f;
        scal[0] = 1.0f / (2.0f * sigma * sigma);
        scal[1] = b2[0]; scal[2] = b2[1]; scal[3] = b2[2]; scal[4] = b2[3];
    }
}

// ---------------------------------------------------------------------------
// rowptr: rp[q] = lower_bound(dst, q) for q in [0, N_Q]  (dst is sorted)
// ---------------------------------------------------------------------------
__global__ void rowptr_kernel(const int* __restrict__ dst, int* __restrict__ rp) {
    int q = blockIdx.x * blockDim.x + threadIdx.x;
    if (q > N_Q) return;
    int lo = 0, hi = NE;
    while (lo < hi) {
        int mid = (lo + hi) >> 1;
        if (dst[mid] < q) lo = mid + 1; else hi = mid;
    }
    rp[q] = lo;
}

// ---------------------------------------------------------------------------
// vproj: v = h_obs @ Wv + bv, fp32 compute, bf16 output.
// ---------------------------------------------------------------------------
__global__ __launch_bounds__(256) void vproj_kernel(const float* __restrict__ h,
                                                    const float* __restrict__ Wv,
                                                    const float* __restrict__ bv,
                                                    unsigned short* __restrict__ v) {
    __shared__ float Ash[64 * 132];
    int t = threadIdx.x;
    int n0 = blockIdx.x * 64;
    #pragma unroll
    for (int rep = 0; rep < 8; ++rep) {
        int idx = rep * 256 + t;
        int row = idx >> 5, c4 = (idx & 31) * 4;
        float4 val = make_float4(0.f, 0.f, 0.f, 0.f);
        if (n0 + row < N_O) val = *(const float4*)(h + (size_t)(n0 + row) * 128 + c4);
        float* d = &Ash[row * 132 + c4];
        d[0] = val.x; d[1] = val.y; d[2] = val.z; d[3] = val.w;
    }
    __syncthreads();

    int cg = t & 15, rg = t >> 4;
    int c0 = cg * 8, r0 = rg * 4;
    float acc[4][8];
    #pragma unroll
    for (int i = 0; i < 4; ++i)
        #pragma unroll
        for (int j = 0; j < 8; ++j) acc[i][j] = 0.f;

    const float4* Wv4 = (const float4*)Wv;
    for (int k = 0; k < 128; ++k) {
        float4 b0 = Wv4[k * 32 + cg * 2];
        float4 b1v = Wv4[k * 32 + cg * 2 + 1];
        float bb[8] = {b0.x, b0.y, b0.z, b0.w, b1v.x, b1v.y, b1v.z, b1v.w};
        #pragma unroll
        for (int i = 0; i < 4; ++i) {
            float a = Ash[(r0 + i) * 132 + k];
            #pragma unroll
            for (int j = 0; j < 8; ++j) acc[i][j] += a * bb[j];
        }
    }

    float bvv[8];
    #pragma unroll
    for (int j = 0; j < 8; ++j) bvv[j] = bv[c0 + j];
    #pragma unroll
    for (int i = 0; i < 4; ++i) {
        int n = n0 + r0 + i;
        if (n < N_O) {
            uint4 o;
            __hip_bfloat162 t0 = __float22bfloat162_rn(
                make_float2(acc[i][0] + bvv[0], acc[i][1] + bvv[1]));
            __hip_bfloat162 t1 = __float22bfloat162_rn(
                make_float2(acc[i][2] + bvv[2], acc[i][3] + bvv[3]));
            __hip_bfloat162 t2 = __float22bfloat162_rn(
                make_float2(acc[i][4] + bvv[4], acc[i][5] + bvv[5]));
            __hip_bfloat162 t3 = __float22bfloat162_rn(
                make_float2(acc[i][6] + bvv[6], acc[i][7] + bvv[7]));
            o.x = *reinterpret_cast<unsigned int*>(&t0);
            o.y = *reinterpret_cast<unsigned int*>(&t1);
            o.z = *reinterpret_cast<unsigned int*>(&t2);
            o.w = *reinterpret_cast<unsigned int*>(&t3);
            *(uint4*)(v + (size_t)n * 128 + c0) = o;
        }
    }
}

// ---------------------------------------------------------------------------
// edge (MFMA): one wave = 32 edges. Output now written to logitsT[4][NE]
// (head-major planes) so attn can vector-load 4 edges' logits per lane.
// ---------------------------------------------------------------------------
__global__ __launch_bounds__(256) void edge_kernel(const float* __restrict__ pos_obs,
                                                   const float* __restrict__ pos_query,
                                                   const int* __restrict__ src,
                                                   const int* __restrict__ dst,
                                                   const unsigned short* __restrict__ W1cT,
                                                   const unsigned short* __restrict__ W2tb,
                                                   const float* __restrict__ scal,
                                                   float* __restrict__ logitsT) {
    __shared__ __align__(16) unsigned char smem[4 * 8448];
    int t = threadIdx.x;
    int wave = t >> 6, lane = t & 63;
    int i = lane & 31, h = lane >> 5;
    unsigned char* myrow = smem + wave * 8448 + i * 264;

    short8 zero8;
    #pragma unroll
    for (int k = 0; k < 8; ++k) zero8[k] = 0;

    short8 a1[4];
    #pragma unroll
    for (int b = 0; b < 4; ++b)
        a1[b] = (h == 0) ? *(const short8*)(W1cT + (32 * b + i) * 8) : zero8;

    short8 a2[8];
    #pragma unroll
    for (int m = 0; m < 8; ++m)
        a2[m] = (i < 4) ? *(const short8*)(W2tb + i * 128 + m * 16 + h * 8) : zero8;

    int e = blockIdx.x * 128 + wave * 32 + i;
    int s = src[e], d = dst[e];
    float pox = pos_obs[s * 3 + 0], poy = pos_obs[s * 3 + 1], poz = pos_obs[s * 3 + 2];
    float pqx = pos_query[d * 3 + 0], pqy = pos_query[d * 3 + 1], pqz = pos_query[d * 3 + 2];
    float rx = pqx - pox, ry = pqy - poy, rz = pqz - poz;
    float dist2 = rx * rx + ry * ry + rz * rz;

    short8 bea = zero8;
    if (h == 0) {
        bea[0] = (short)f2bf(pqx); bea[1] = (short)f2bf(pqy); bea[2] = (short)f2bf(pqz);
        bea[3] = (short)f2bf(pox); bea[4] = (short)f2bf(poy); bea[5] = (short)f2bf(poz);
        bea[6] = (short)0x3F80;    // 1.0 bf16 (bias attr)
        bea[7] = 0;
    }

    // GEMM1
    f32x16 c1[4];
    #pragma unroll
    for (int b = 0; b < 4; ++b) {
        #pragma unroll
        for (int k = 0; k < 16; ++k) c1[b][k] = 0.0f;
        c1[b] = __builtin_amdgcn_mfma_f32_32x32x16_bf16(a1[b], bea, c1[b], 0, 0, 0);
    }

    // relu -> bf16 -> LDS  (reg r+4s -> hidden 32b + 8s + 4h + r)
    #pragma unroll
    for (int b = 0; b < 4; ++b) {
        #pragma unroll
        for (int s_ = 0; s_ < 4; ++s_) {
            float x0 = fmaxf(c1[b][4 * s_ + 0], 0.f);
            float x1 = fmaxf(c1[b][4 * s_ + 1], 0.f);
            float x2 = fmaxf(c1[b][4 * s_ + 2], 0.f);
            float x3 = fmaxf(c1[b][4 * s_ + 3], 0.f);
            __hip_bfloat162 p0 = __float22bfloat162_rn(make_float2(x0, x1));
            __hip_bfloat162 p1 = __float22bfloat162_rn(make_float2(x2, x3));
            uint2 w;
            w.x = *reinterpret_cast<unsigned int*>(&p0);
            w.y = *reinterpret_cast<unsigned int*>(&p1);
            *(uint2*)(myrow + 64 * b + 16 * s_ + 8 * h) = w;
        }
    }

    // GEMM2
    f32x16 c2;
    #pragma unroll
    for (int k = 0; k < 16; ++k) c2[k] = 0.0f;
    #pragma unroll
    for (int m = 0; m < 8; ++m) {
        uint2 lo = *(const uint2*)(myrow + 32 * m + 16 * h);
        uint2 hi = *(const uint2*)(myrow + 32 * m + 16 * h + 8);
        union { unsigned int u[4]; short8 s; } bf;
        bf.u[0] = lo.x; bf.u[1] = lo.y; bf.u[2] = hi.x; bf.u[3] = hi.y;
        c2 = __builtin_amdgcn_mfma_f32_32x32x16_bf16(a2[m], bf.s, c2, 0, 0, 0);
    }

    if (h == 0) {
        float pen = dist2 * scal[0];
        logitsT[0 * NE + e] = c2[0] + scal[1] - pen;
        logitsT[1 * NE + e] = c2[1] + scal[2] - pen;
        logitsT[2 * NE + e] = c2[2] + scal[3] - pen;
        logitsT[3 * NE + e] = c2[3] + scal[4] - pen;
    }
}

// ---------------------------------------------------------------------------
// attn: one wave per query. __expf softmax over head-major logit planes,
// unroll-4 phase B with float4 logit loads + int4 src loads; denom folded
// into the final store.
// ---------------------------------------------------------------------------
__global__ __launch_bounds__(256) void attn_kernel(const __hip_bfloat162* __restrict__ vb,
                                                   const float* __restrict__ logitsT,
                                                   const int* __restrict__ src,
                                                   const int* __restrict__ rp,
                                                   float* __restrict__ out) {
    int t = threadIdx.x;
    int lane = t & 63;
    int q = blockIdx.x * 4 + (t >> 6);
    int s0 = rp[q], s1 = rp[q + 1];
    int h = lane >> 4, i = lane & 15;
    const float* lp = logitsT + (size_t)h * NE;

    float m = -INFINITY;
    for (int e = s0 + i; e < s1; e += 16) m = fmaxf(m, lp[e]);
    #pragma unroll
    for (int off = 8; off; off >>= 1) m = fmaxf(m, __shfl_xor(m, off));

    float sum = 0.f;
    for (int e = s0 + i; e < s1; e += 16) sum += __expf(lp[e] - m);
    #pragma unroll
    for (int off = 8; off; off >>= 1) sum += __shfl_xor(sum, off);
    float r = 1.0f / (sum + 1e-16f);

    // phase B: lane owns channels 2*lane, 2*lane+1; (lane*2)>>5 == lane>>4 == h
    float acc0 = 0.f, acc1 = 0.f;
    int e = s0;
    for (; e < s1 && (e & 3); ++e) {          // align to 16 B for float4/int4
        float w = __expf(lp[e] - m);
        float2 f = __bfloat1622float2(vb[(size_t)src[e] * 64 + lane]);
        acc0 += w * f.x; acc1 += w * f.y;
    }
    for (; e + 4 <= s1; e += 4) {
        float4 l4 = *(const float4*)(lp + e);
        int4 s4 = *(const int4*)(src + e);
        float w0 = __expf(l4.x - m);
        float w1 = __expf(l4.y - m);
        float w2 = __expf(l4.z - m);
        float w3 = __expf(l4.w - m);
        float2 f0 = __bfloat1622float2(vb[(size_t)s4.x * 64 + lane]);
        float2 f1 = __bfloat1622float2(vb[(size_t)s4.y * 64 + lane]);
        float2 f2 = __bfloat1622float2(vb[(size_t)s4.z * 64 + lane]);
        float2 f3 = __bfloat1622float2(vb[(size_t)s4.w * 64 + lane]);
        acc0 += w0 * f0.x + w1 * f1.x + w2 * f2.x + w3 * f3.x;
        acc1 += w0 * f0.y + w1 * f1.y + w2 * f2.y + w3 * f3.y;
    }
    for (; e < s1; ++e) {
        float w = __expf(lp[e] - m);
        float2 f = __bfloat1622float2(vb[(size_t)src[e] * 64 + lane]);
        acc0 += w * f.x; acc1 += w * f.y;
    }
    *(float2*)(out + (size_t)q * 128 + lane * 2) = make_float2(acc0 * r, acc1 * r);
}

// ---------------------------------------------------------------------------
extern "C" void kernel_launch(void* const* d_in, const int* in_sizes, int n_in,
                              void* d_out, int out_size, void* d_ws, size_t ws_size,
                              hipStream_t stream) {
    const float* h_obs     = (const float*)d_in[0];
    const float* pos_obs   = (const float*)d_in[1];
    const float* pos_query = (const float*)d_in[2];
    const int*   src       = (const int*)d_in[3];
    const int*   dst       = (const int*)d_in[4];
    const float* W1        = (const float*)d_in[5];
    const float* b1        = (const float*)d_in[6];
    const float* W2        = (const float*)d_in[7];
    const float* b2        = (const float*)d_in[8];
    const float* Wv        = (const float*)d_in[9];
    const float* bv        = (const float*)d_in[10];
    const float* log_sigma = (const float*)d_in[11];
    float* out = (float*)d_out;

    char* ws = (char*)d_ws;
    int*            rp      = (int*)(ws + 0);                   // 50001 ints  (end 200004)
    float*          scal    = (float*)(ws + 200192);            // 8 floats    (end 200224)
    unsigned short* W1cT    = (unsigned short*)(ws + 200256);   // 1024 bf16   (end 202304)
    unsigned short* W2tb    = (unsigned short*)(ws + 202304);   // 512 bf16    (end 203328)
    unsigned short* vbuf    = (unsigned short*)(ws + 208640);   // 6.4M bf16   (end 13,008,640)
    float*          logitsT = (float*)(ws + 13008768);          // 6.4M floats (end 38,608,768)

    hipLaunchKernelGGL(pack_kernel, dim3(1), dim3(256), 0, stream,
                       W1, b1, W2, b2, log_sigma, W1cT, W2tb, scal);
    hipLaunchKernelGGL(rowptr_kernel, dim3((N_Q + 256) / 256), dim3(256), 0, stream,
                       dst, rp);
    hipLaunchKernelGGL(vproj_kernel, dim3((N_O + 63) / 64), dim3(256), 0, stream,
                       h_obs, Wv, bv, vbuf);
    hipLaunchKernelGGL(edge_kernel, dim3(NE / 128), dim3(256), 0, stream,
                       pos_obs, pos_query, src, dst, W1cT, W2tb, scal, logitsT);
    hipLaunchKernelGGL(attn_kernel, dim3(N_Q / 4), dim3(256), 0, stream,
                       (const __hip_bfloat162*)vbuf, logitsT, src, rp, out);
}

// Round 6
// 249.098 us; speedup vs baseline: 1.9580x; 1.0334x over previous
//
#include <hip/hip_runtime.h>
#include <hip/hip_bf16.h>
#include <cstdint>
#include <cstddef>

#define N_O 50000
#define N_Q 50000
#define NE  1600000
// LATENT=128, HEADS=4, HEAD_DIM=32

#define EDGE_BLOCKS  (NE / 128)            // 12500
#define VP_BLOCKS    ((N_O + 63) / 64)     // 782
#define RP_BLOCKS    ((N_Q + 256) / 256)   // 196
#define WCAP 264                           // attn LDS plane stride (floats)

typedef __attribute__((ext_vector_type(8)))  short short8;
typedef __attribute__((ext_vector_type(16))) float f32x16;

__device__ inline unsigned short f2bf(float x) {
    __hip_bfloat16 hb = __float2bfloat16(x);
    return *reinterpret_cast<unsigned short*>(&hb);
}

// ---------------------------------------------------------------------------
// pack: build bf16 weight tensors for the MFMA edge MLP.
//  W1cT [128 hidden][8 attr] bf16 : attrs = [Wq+Wr (3), Wo-Wr (3), b1, 0]
//  W2tb [4 head][128 hidden] bf16
//  scal fp32: [0]=1/(2 sigma^2), [1..4]=b2
// ---------------------------------------------------------------------------
__global__ void pack_kernel(const float* __restrict__ W1, const float* __restrict__ b1,
                            const float* __restrict__ W2, const float* __restrict__ b2,
                            const float* __restrict__ log_sigma,
                            unsigned short* __restrict__ W1cT,
                            unsigned short* __restrict__ W2tb,
                            float* __restrict__ scal) {
    int j = threadIdx.x;
    if (j < 128) {
        #pragma unroll
        for (int a = 0; a < 3; ++a) {
            W1cT[j * 8 + a]     = f2bf(W1[(3 + a) * 128 + j] + W1[a * 128 + j]); // pq coef
            W1cT[j * 8 + 3 + a] = f2bf(W1[(6 + a) * 128 + j] - W1[a * 128 + j]); // po coef
        }
        W1cT[j * 8 + 6] = f2bf(b1[j]);
        W1cT[j * 8 + 7] = 0;
        #pragma unroll
        for (int hd = 0; hd < 4; ++hd)
            W2tb[hd * 128 + j] = f2bf(W2[j * 4 + hd]);
    } else if (j == 128) {
        float sigma = expf(log_sigma[0]) + 1e-6f;
        scal[0] = 1.0f / (2.0f * sigma * sigma);
        scal[1] = b2[0]; scal[2] = b2[1]; scal[3] = b2[2]; scal[4] = b2[3];
    }
}

// ---------------------------------------------------------------------------
// rowptr body: rp[q] = lower_bound(dst, q)
// ---------------------------------------------------------------------------
__device__ void rowptr_body(int bid, const int* __restrict__ dst, int* __restrict__ rp) {
    int q = bid * 256 + threadIdx.x;
    if (q > N_Q) return;
    int lo = 0, hi = NE;
    while (lo < hi) {
        int mid = (lo + hi) >> 1;
        if (dst[mid] < q) lo = mid + 1; else hi = mid;
    }
    rp[q] = lo;
}

// ---------------------------------------------------------------------------
// vproj body: v = h_obs @ Wv + bv, fp32 compute, bf16 output.
// ---------------------------------------------------------------------------
__device__ void vproj_body(int bid, const float* __restrict__ h,
                           const float* __restrict__ Wv,
                           const float* __restrict__ bv,
                           unsigned short* __restrict__ v,
                           float* Ash /* 64*132 floats */) {
    int t = threadIdx.x;
    int n0 = bid * 64;
    #pragma unroll
    for (int rep = 0; rep < 8; ++rep) {
        int idx = rep * 256 + t;
        int row = idx >> 5, c4 = (idx & 31) * 4;
        float4 val = make_float4(0.f, 0.f, 0.f, 0.f);
        if (n0 + row < N_O) val = *(const float4*)(h + (size_t)(n0 + row) * 128 + c4);
        float* d = &Ash[row * 132 + c4];
        d[0] = val.x; d[1] = val.y; d[2] = val.z; d[3] = val.w;
    }
    __syncthreads();

    int cg = t & 15, rg = t >> 4;
    int c0 = cg * 8, r0 = rg * 4;
    float acc[4][8];
    #pragma unroll
    for (int i = 0; i < 4; ++i)
        #pragma unroll
        for (int j = 0; j < 8; ++j) acc[i][j] = 0.f;

    const float4* Wv4 = (const float4*)Wv;
    for (int k = 0; k < 128; ++k) {
        float4 b0 = Wv4[k * 32 + cg * 2];
        float4 b1v = Wv4[k * 32 + cg * 2 + 1];
        float bb[8] = {b0.x, b0.y, b0.z, b0.w, b1v.x, b1v.y, b1v.z, b1v.w};
        #pragma unroll
        for (int i = 0; i < 4; ++i) {
            float a = Ash[(r0 + i) * 132 + k];
            #pragma unroll
            for (int j = 0; j < 8; ++j) acc[i][j] += a * bb[j];
        }
    }

    float bvv[8];
    #pragma unroll
    for (int j = 0; j < 8; ++j) bvv[j] = bv[c0 + j];
    #pragma unroll
    for (int i = 0; i < 4; ++i) {
        int n = n0 + r0 + i;
        if (n < N_O) {
            uint4 o;
            __hip_bfloat162 t0 = __float22bfloat162_rn(
                make_float2(acc[i][0] + bvv[0], acc[i][1] + bvv[1]));
            __hip_bfloat162 t1 = __float22bfloat162_rn(
                make_float2(acc[i][2] + bvv[2], acc[i][3] + bvv[3]));
            __hip_bfloat162 t2 = __float22bfloat162_rn(
                make_float2(acc[i][4] + bvv[4], acc[i][5] + bvv[5]));
            __hip_bfloat162 t3 = __float22bfloat162_rn(
                make_float2(acc[i][6] + bvv[6], acc[i][7] + bvv[7]));
            o.x = *reinterpret_cast<unsigned int*>(&t0);
            o.y = *reinterpret_cast<unsigned int*>(&t1);
            o.z = *reinterpret_cast<unsigned int*>(&t2);
            o.w = *reinterpret_cast<unsigned int*>(&t3);
            *(uint4*)(v + (size_t)n * 128 + c0) = o;
        }
    }
}

// ---------------------------------------------------------------------------
// edge body (MFMA): one wave = 32 edges; logits to head-major planes.
// ---------------------------------------------------------------------------
__device__ void edge_body(int bid, const float* __restrict__ pos_obs,
                          const float* __restrict__ pos_query,
                          const int* __restrict__ src,
                          const int* __restrict__ dst,
                          const unsigned short* __restrict__ W1cT,
                          const unsigned short* __restrict__ W2tb,
                          const float* __restrict__ scal,
                          float* __restrict__ logitsT,
                          unsigned char* smem /* 4*8448 bytes */) {
    int t = threadIdx.x;
    int wave = t >> 6, lane = t & 63;
    int i = lane & 31, h = lane >> 5;
    unsigned char* myrow = smem + wave * 8448 + i * 264;

    short8 zero8;
    #pragma unroll
    for (int k = 0; k < 8; ++k) zero8[k] = 0;

    short8 a1[4];
    #pragma unroll
    for (int b = 0; b < 4; ++b)
        a1[b] = (h == 0) ? *(const short8*)(W1cT + (32 * b + i) * 8) : zero8;

    short8 a2[8];
    #pragma unroll
    for (int m = 0; m < 8; ++m)
        a2[m] = (i < 4) ? *(const short8*)(W2tb + i * 128 + m * 16 + h * 8) : zero8;

    int e = bid * 128 + wave * 32 + i;
    int s = src[e], d = dst[e];
    float pox = pos_obs[s * 3 + 0], poy = pos_obs[s * 3 + 1], poz = pos_obs[s * 3 + 2];
    float pqx = pos_query[d * 3 + 0], pqy = pos_query[d * 3 + 1], pqz = pos_query[d * 3 + 2];
    float rx = pqx - pox, ry = pqy - poy, rz = pqz - poz;
    float dist2 = rx * rx + ry * ry + rz * rz;

    short8 bea = zero8;
    if (h == 0) {
        bea[0] = (short)f2bf(pqx); bea[1] = (short)f2bf(pqy); bea[2] = (short)f2bf(pqz);
        bea[3] = (short)f2bf(pox); bea[4] = (short)f2bf(poy); bea[5] = (short)f2bf(poz);
        bea[6] = (short)0x3F80;    // 1.0 bf16 (bias attr)
        bea[7] = 0;
    }

    // GEMM1
    f32x16 c1[4];
    #pragma unroll
    for (int b = 0; b < 4; ++b) {
        #pragma unroll
        for (int k = 0; k < 16; ++k) c1[b][k] = 0.0f;
        c1[b] = __builtin_amdgcn_mfma_f32_32x32x16_bf16(a1[b], bea, c1[b], 0, 0, 0);
    }

    // relu -> bf16 -> LDS  (reg r+4s -> hidden 32b + 8s + 4h + r)
    #pragma unroll
    for (int b = 0; b < 4; ++b) {
        #pragma unroll
        for (int s_ = 0; s_ < 4; ++s_) {
            float x0 = fmaxf(c1[b][4 * s_ + 0], 0.f);
            float x1 = fmaxf(c1[b][4 * s_ + 1], 0.f);
            float x2 = fmaxf(c1[b][4 * s_ + 2], 0.f);
            float x3 = fmaxf(c1[b][4 * s_ + 3], 0.f);
            __hip_bfloat162 p0 = __float22bfloat162_rn(make_float2(x0, x1));
            __hip_bfloat162 p1 = __float22bfloat162_rn(make_float2(x2, x3));
            uint2 w;
            w.x = *reinterpret_cast<unsigned int*>(&p0);
            w.y = *reinterpret_cast<unsigned int*>(&p1);
            *(uint2*)(myrow + 64 * b + 16 * s_ + 8 * h) = w;
        }
    }

    // GEMM2
    f32x16 c2;
    #pragma unroll
    for (int k = 0; k < 16; ++k) c2[k] = 0.0f;
    #pragma unroll
    for (int m = 0; m < 8; ++m) {
        uint2 lo = *(const uint2*)(myrow + 32 * m + 16 * h);
        uint2 hi = *(const uint2*)(myrow + 32 * m + 16 * h + 8);
        union { unsigned int u[4]; short8 s; } bf;
        bf.u[0] = lo.x; bf.u[1] = lo.y; bf.u[2] = hi.x; bf.u[3] = hi.y;
        c2 = __builtin_amdgcn_mfma_f32_32x32x16_bf16(a2[m], bf.s, c2, 0, 0, 0);
    }

    if (h == 0) {
        float pen = dist2 * scal[0];
        logitsT[0 * NE + e] = c2[0] + scal[1] - pen;
        logitsT[1 * NE + e] = c2[1] + scal[2] - pen;
        logitsT[2 * NE + e] = c2[2] + scal[3] - pen;
        logitsT[3 * NE + e] = c2[3] + scal[4] - pen;
    }
}

// ---------------------------------------------------------------------------
// fused: edge | vproj | rowptr partitioned by blockIdx (mutually independent)
// ---------------------------------------------------------------------------
__global__ __launch_bounds__(256) void fused_kernel(const float* __restrict__ pos_obs,
                                                    const float* __restrict__ pos_query,
                                                    const int* __restrict__ src,
                                                    const int* __restrict__ dst,
                                                    const unsigned short* __restrict__ W1cT,
                                                    const unsigned short* __restrict__ W2tb,
                                                    const float* __restrict__ scal,
                                                    float* __restrict__ logitsT,
                                                    const float* __restrict__ h_obs,
                                                    const float* __restrict__ Wv,
                                                    const float* __restrict__ bv,
                                                    unsigned short* __restrict__ vbuf,
                                                    int* __restrict__ rp) {
    __shared__ __align__(16) unsigned char smem[33792];  // 4*8448 == 64*132*4
    int b = blockIdx.x;
    if (b < EDGE_BLOCKS) {
        edge_body(b, pos_obs, pos_query, src, dst, W1cT, W2tb, scal, logitsT, smem);
    } else if (b < EDGE_BLOCKS + VP_BLOCKS) {
        vproj_body(b - EDGE_BLOCKS, h_obs, Wv, bv, vbuf, (float*)smem);
    } else {
        rowptr_body(b - EDGE_BLOCKS - VP_BLOCKS, dst, rp);
    }
}

// ---------------------------------------------------------------------------
// attn: one wave per query. Sum pass stores unnormalized exp weights into a
// per-wave per-head LDS plane (stride WCAP=264 floats -> 16B-aligned b128
// reads, conflict-free); phase B reads weights from LDS (no v_exp) and does
// coalesced bf16 v-row reads. Legacy inline-exp path for cnt > 256.
// ---------------------------------------------------------------------------
__global__ __launch_bounds__(256) void attn_kernel(const __hip_bfloat162* __restrict__ vb,
                                                   const float* __restrict__ logitsT,
                                                   const int* __restrict__ src,
                                                   const int* __restrict__ rp,
                                                   float* __restrict__ out) {
    __shared__ __align__(16) float wsh[4 * 4 * WCAP];   // 16896 B
    int t = threadIdx.x;
    int lane = t & 63, wave = t >> 6;
    int q = blockIdx.x * 4 + wave;
    int s0 = rp[q], s1 = rp[q + 1];
    int cnt = s1 - s0;
    int h = lane >> 4, i = lane & 15;
    const float* lp = logitsT + (size_t)h * NE;

    // max pass (within each 16-lane head group)
    float m = -INFINITY;
    for (int e = s0 + i; e < s1; e += 16) m = fmaxf(m, lp[e]);
    #pragma unroll
    for (int off = 8; off; off >>= 1) m = fmaxf(m, __shfl_xor(m, off));

    float acc0 = 0.f, acc1 = 0.f, r;

    if (cnt <= 256) {
        int s0a = s0 & ~3;
        float* wpb = wsh + wave * (4 * WCAP) + h * WCAP;  // index with (e - s0a), max 259 < WCAP
        float sum = 0.f;
        for (int e = s0 + i; e < s1; e += 16) {
            float w = __expf(lp[e] - m);
            wpb[e - s0a] = w;
            sum += w;
        }
        #pragma unroll
        for (int off = 8; off; off >>= 1) sum += __shfl_xor(sum, off);
        r = 1.0f / (sum + 1e-16f);
        // same-wave LDS RAW; compiler inserts lgkmcnt waits, no barrier needed.

        int e = s0;
        int e1 = (s0 + 3) & ~3; if (e1 > s1) e1 = s1;
        for (; e < e1; ++e) {                 // align absolute e to 4
            float w = wpb[e - s0a];
            float2 f = __bfloat1622float2(vb[(size_t)src[e] * 64 + lane]);
            acc0 += w * f.x; acc1 += w * f.y;
        }
        for (; e + 4 <= s1; e += 4) {
            float4 w4 = *(const float4*)(wpb + (e - s0a));   // ds_read_b128, aligned
            int4 s4 = *(const int4*)(src + e);
            float2 f0 = __bfloat1622float2(vb[(size_t)s4.x * 64 + lane]);
            float2 f1 = __bfloat1622float2(vb[(size_t)s4.y * 64 + lane]);
            float2 f2 = __bfloat1622float2(vb[(size_t)s4.z * 64 + lane]);
            float2 f3 = __bfloat1622float2(vb[(size_t)s4.w * 64 + lane]);
            acc0 += w4.x * f0.x + w4.y * f1.x + w4.z * f2.x + w4.w * f3.x;
            acc1 += w4.x * f0.y + w4.y * f1.y + w4.z * f2.y + w4.w * f3.y;
        }
        for (; e < s1; ++e) {
            float w = wpb[e - s0a];
            float2 f = __bfloat1622float2(vb[(size_t)src[e] * 64 + lane]);
            acc0 += w * f.x; acc1 += w * f.y;
        }
    } else {
        // legacy path (never expected at lambda=32, kept for correctness)
        float sum = 0.f;
        for (int e = s0 + i; e < s1; e += 16) sum += __expf(lp[e] - m);
        #pragma unroll
        for (int off = 8; off; off >>= 1) sum += __shfl_xor(sum, off);
        r = 1.0f / (sum + 1e-16f);

        int e = s0;
        for (; e < s1 && (e & 3); ++e) {
            float w = __expf(lp[e] - m);
            float2 f = __bfloat1622float2(vb[(size_t)src[e] * 64 + lane]);
            acc0 += w * f.x; acc1 += w * f.y;
        }
        for (; e + 4 <= s1; e += 4) {
            float4 l4 = *(const float4*)(lp + e);
            int4 s4 = *(const int4*)(src + e);
            float w0 = __expf(l4.x - m);
            float w1 = __expf(l4.y - m);
            float w2 = __expf(l4.z - m);
            float w3 = __expf(l4.w - m);
            float2 f0 = __bfloat1622float2(vb[(size_t)s4.x * 64 + lane]);
            float2 f1 = __bfloat1622float2(vb[(size_t)s4.y * 64 + lane]);
            float2 f2 = __bfloat1622float2(vb[(size_t)s4.z * 64 + lane]);
            float2 f3 = __bfloat1622float2(vb[(size_t)s4.w * 64 + lane]);
            acc0 += w0 * f0.x + w1 * f1.x + w2 * f2.x + w3 * f3.x;
            acc1 += w0 * f0.y + w1 * f1.y + w2 * f2.y + w3 * f3.y;
        }
        for (; e < s1; ++e) {
            float w = __expf(lp[e] - m);
            float2 f = __bfloat1622float2(vb[(size_t)src[e] * 64 + lane]);
            acc0 += w * f.x; acc1 += w * f.y;
        }
    }
    *(float2*)(out + (size_t)q * 128 + lane * 2) = make_float2(acc0 * r, acc1 * r);
}

// ---------------------------------------------------------------------------
extern "C" void kernel_launch(void* const* d_in, const int* in_sizes, int n_in,
                              void* d_out, int out_size, void* d_ws, size_t ws_size,
                              hipStream_t stream) {
    const float* h_obs     = (const float*)d_in[0];
    const float* pos_obs   = (const float*)d_in[1];
    const float* pos_query = (const float*)d_in[2];
    const int*   src       = (const int*)d_in[3];
    const int*   dst       = (const int*)d_in[4];
    const float* W1        = (const float*)d_in[5];
    const float* b1        = (const float*)d_in[6];
    const float* W2        = (const float*)d_in[7];
    const float* b2        = (const float*)d_in[8];
    const float* Wv        = (const float*)d_in[9];
    const float* bv        = (const float*)d_in[10];
    const float* log_sigma = (const float*)d_in[11];
    float* out = (float*)d_out;

    char* ws = (char*)d_ws;
    int*            rp      = (int*)(ws + 0);                   // 50001 ints  (end 200004)
    float*          scal    = (float*)(ws + 200192);            // 8 floats    (end 200224)
    unsigned short* W1cT    = (unsigned short*)(ws + 200256);   // 1024 bf16   (end 202304)
    unsigned short* W2tb    = (unsigned short*)(ws + 202304);   // 512 bf16    (end 203328)
    unsigned short* vbuf    = (unsigned short*)(ws + 208640);   // 6.4M bf16   (end 13,008,640)
    float*          logitsT = (float*)(ws + 13008768);          // 6.4M floats (end 38,608,768)

    hipLaunchKernelGGL(pack_kernel, dim3(1), dim3(256), 0, stream,
                       W1, b1, W2, b2, log_sigma, W1cT, W2tb, scal);
    hipLaunchKernelGGL(fused_kernel, dim3(EDGE_BLOCKS + VP_BLOCKS + RP_BLOCKS),
                       dim3(256), 0, stream,
                       pos_obs, pos_query, src, dst, W1cT, W2tb, scal, logitsT,
                       h_obs, Wv, bv, vbuf, rp);
    hipLaunchKernelGGL(attn_kernel, dim3(N_Q / 4), dim3(256), 0, stream,
                       (const __hip_bfloat162*)vbuf, logitsT, src, rp, out);
}

// Round 10
// 248.969 us; speedup vs baseline: 1.9590x; 1.0005x over previous
//
#include <hip/hip_runtime.h>
#include <hip/hip_bf16.h>
#include <cstdint>
#include <cstddef>

#define N_O 50000
#define N_Q 50000
#define NE  1600000
// LATENT=128, HEADS=4, HEAD_DIM=32

#define EDGE_BLOCKS  (NE / 64)             // 25000 (2 waves x 32 edges per block)
#define VP_BLOCKS    ((N_O + 63) / 64)     // 782
#define RP_BLOCKS    ((N_Q + 256) / 256)   // 196
#define WCAP 264                           // attn LDS plane stride (floats)

typedef __attribute__((ext_vector_type(8)))  short short8;
typedef __attribute__((ext_vector_type(16))) float f32x16;

__device__ inline unsigned short f2bf(float x) {
    __hip_bfloat16 hb = __float2bfloat16(x);
    return *reinterpret_cast<unsigned short*>(&hb);
}

// ---------------------------------------------------------------------------
// pack (R6-proven): bf16 weight tensors for the MFMA edge MLP.
//  W1cT [128 hidden][8 attr] bf16 : attrs = [Wq+Wr (3), Wo-Wr (3), b1, 0]
//  W2tb [4 head][128 hidden] bf16
//  scal fp32: [0]=1/(2 sigma^2), [1..4]=b2
// ---------------------------------------------------------------------------
__global__ void pack_kernel(const float* __restrict__ W1, const float* __restrict__ b1,
                            const float* __restrict__ W2, const float* __restrict__ b2,
                            const float* __restrict__ log_sigma,
                            unsigned short* __restrict__ W1cT,
                            unsigned short* __restrict__ W2tb,
                            float* __restrict__ scal) {
    int j = threadIdx.x;
    if (j < 128) {
        #pragma unroll
        for (int a = 0; a < 3; ++a) {
            W1cT[j * 8 + a]     = f2bf(W1[(3 + a) * 128 + j] + W1[a * 128 + j]); // pq coef
            W1cT[j * 8 + 3 + a] = f2bf(W1[(6 + a) * 128 + j] - W1[a * 128 + j]); // po coef
        }
        W1cT[j * 8 + 6] = f2bf(b1[j]);
        W1cT[j * 8 + 7] = 0;
        #pragma unroll
        for (int hd = 0; hd < 4; ++hd)
            W2tb[hd * 128 + j] = f2bf(W2[j * 4 + hd]);
    } else if (j == 128) {
        float sigma = expf(log_sigma[0]) + 1e-6f;
        scal[0] = 1.0f / (2.0f * sigma * sigma);
        scal[1] = b2[0]; scal[2] = b2[1]; scal[3] = b2[2]; scal[4] = b2[3];
    }
}

// ---------------------------------------------------------------------------
// rowptr body (R6-proven): rp[q] = lower_bound(dst, q)
// ---------------------------------------------------------------------------
__device__ void rowptr_body(int bid, const int* __restrict__ dst, int* __restrict__ rp) {
    int q = bid * 256 + threadIdx.x;
    if (q > N_Q) return;
    int lo = 0, hi = NE;
    while (lo < hi) {
        int mid = (lo + hi) >> 1;
        if (dst[mid] < q) lo = mid + 1; else hi = mid;
    }
    rp[q] = lo;
}

// ---------------------------------------------------------------------------
// vproj body (R6-proven): v = h_obs @ Wv + bv, fp32 compute, bf16 output.
// 64 rows/block, 256 threads, 4x8 outputs per thread.
// ---------------------------------------------------------------------------
__device__ void vproj_body(int bid, const float* __restrict__ h,
                           const float* __restrict__ Wv,
                           const float* __restrict__ bv,
                           unsigned short* __restrict__ v,
                           float* Ash /* 64*132 floats */) {
    int t = threadIdx.x;
    int n0 = bid * 64;
    #pragma unroll
    for (int rep = 0; rep < 8; ++rep) {
        int idx = rep * 256 + t;
        int row = idx >> 5, c4 = (idx & 31) * 4;
        float4 val = make_float4(0.f, 0.f, 0.f, 0.f);
        if (n0 + row < N_O) val = *(const float4*)(h + (size_t)(n0 + row) * 128 + c4);
        float* d = &Ash[row * 132 + c4];
        d[0] = val.x; d[1] = val.y; d[2] = val.z; d[3] = val.w;
    }
    __syncthreads();

    int cg = t & 15, rg = t >> 4;
    int c0 = cg * 8, r0 = rg * 4;
    float acc[4][8];
    #pragma unroll
    for (int i = 0; i < 4; ++i)
        #pragma unroll
        for (int j = 0; j < 8; ++j) acc[i][j] = 0.f;

    const float4* Wv4 = (const float4*)Wv;
    for (int k = 0; k < 128; ++k) {
        float4 b0 = Wv4[k * 32 + cg * 2];
        float4 b1v = Wv4[k * 32 + cg * 2 + 1];
        float bb[8] = {b0.x, b0.y, b0.z, b0.w, b1v.x, b1v.y, b1v.z, b1v.w};
        #pragma unroll
        for (int i = 0; i < 4; ++i) {
            float a = Ash[(r0 + i) * 132 + k];
            #pragma unroll
            for (int j = 0; j < 8; ++j) acc[i][j] += a * bb[j];
        }
    }

    float bvv[8];
    #pragma unroll
    for (int j = 0; j < 8; ++j) bvv[j] = bv[c0 + j];
    #pragma unroll
    for (int i = 0; i < 4; ++i) {
        int n = n0 + r0 + i;
        if (n < N_O) {
            uint4 o;
            __hip_bfloat162 t0 = __float22bfloat162_rn(
                make_float2(acc[i][0] + bvv[0], acc[i][1] + bvv[1]));
            __hip_bfloat162 t1 = __float22bfloat162_rn(
                make_float2(acc[i][2] + bvv[2], acc[i][3] + bvv[3]));
            __hip_bfloat162 t2 = __float22bfloat162_rn(
                make_float2(acc[i][4] + bvv[4], acc[i][5] + bvv[5]));
            __hip_bfloat162 t3 = __float22bfloat162_rn(
                make_float2(acc[i][6] + bvv[6], acc[i][7] + bvv[7]));
            o.x = *reinterpret_cast<unsigned int*>(&t0);
            o.y = *reinterpret_cast<unsigned int*>(&t1);
            o.z = *reinterpret_cast<unsigned int*>(&t2);
            o.w = *reinterpret_cast<unsigned int*>(&t3);
            *(uint4*)(v + (size_t)n * 128 + c0) = o;
        }
    }
}

// ---------------------------------------------------------------------------
// fusedVR: vproj | rowptr partitioned by blockIdx (both R6-proven bodies)
// ---------------------------------------------------------------------------
__global__ __launch_bounds__(256) void fusedVR_kernel(
        const int* __restrict__ dst,
        const float* __restrict__ h_obs, const float* __restrict__ Wv,
        const float* __restrict__ bv, unsigned short* __restrict__ vbuf,
        int* __restrict__ rp) {
    __shared__ __align__(16) float Ash[64 * 132];   // 33792 B
    int b = blockIdx.x;
    if (b < VP_BLOCKS) {
        vproj_body(b, h_obs, Wv, bv, vbuf, Ash);
    } else {
        rowptr_body(b - VP_BLOCKS, dst, rp);
    }
}

// ---------------------------------------------------------------------------
// edge (R6-proven body, now 2 waves/block for occupancy): one wave = 32
// edges. GEMM1 (4x 32x32x16) -> relu/bf16 -> per-wave LDS tile [32][264 B]
// -> GEMM2 (8x 32x32x16, K=128). LDS 16896 B/block, VGPR ~84 ->
// ~18 waves/CU resident (vs ~9 when fused with vproj at 33792 B).
// ---------------------------------------------------------------------------
__global__ __launch_bounds__(128) void edge_kernel(
        const float* __restrict__ pos_obs, const float* __restrict__ pos_query,
        const int* __restrict__ src, const int* __restrict__ dst,
        const unsigned short* __restrict__ W1cT,
        const unsigned short* __restrict__ W2tb,
        const float* __restrict__ scal, float* __restrict__ logitsT) {
    __shared__ __align__(16) unsigned char smem[2 * 8448];
    int t = threadIdx.x;
    int wave = t >> 6, lane = t & 63;
    int i = lane & 31, h = lane >> 5;
    unsigned char* myrow = smem + wave * 8448 + i * 264;

    short8 zero8;
    #pragma unroll
    for (int k = 0; k < 8; ++k) zero8[k] = 0;

    short8 a1[4];
    #pragma unroll
    for (int b = 0; b < 4; ++b)
        a1[b] = (h == 0) ? *(const short8*)(W1cT + (32 * b + i) * 8) : zero8;

    short8 a2[8];
    #pragma unroll
    for (int m = 0; m < 8; ++m)
        a2[m] = (i < 4) ? *(const short8*)(W2tb + i * 128 + m * 16 + h * 8) : zero8;

    int e = blockIdx.x * 64 + wave * 32 + i;
    int s = src[e], d = dst[e];
    float pox = pos_obs[s * 3 + 0], poy = pos_obs[s * 3 + 1], poz = pos_obs[s * 3 + 2];
    float pqx = pos_query[d * 3 + 0], pqy = pos_query[d * 3 + 1], pqz = pos_query[d * 3 + 2];
    float rx = pqx - pox, ry = pqy - poy, rz = pqz - poz;
    float dist2 = rx * rx + ry * ry + rz * rz;

    short8 bea = zero8;
    if (h == 0) {
        bea[0] = (short)f2bf(pqx); bea[1] = (short)f2bf(pqy); bea[2] = (short)f2bf(pqz);
        bea[3] = (short)f2bf(pox); bea[4] = (short)f2bf(poy); bea[5] = (short)f2bf(poz);
        bea[6] = (short)0x3F80;    // 1.0 bf16 (bias attr)
        bea[7] = 0;
    }

    // GEMM1
    f32x16 c1[4];
    #pragma unroll
    for (int b = 0; b < 4; ++b) {
        #pragma unroll
        for (int k = 0; k < 16; ++k) c1[b][k] = 0.0f;
        c1[b] = __builtin_amdgcn_mfma_f32_32x32x16_bf16(a1[b], bea, c1[b], 0, 0, 0);
    }

    // relu -> bf16 -> LDS  (reg r+4s -> hidden 32b + 8s + 4h + r)
    #pragma unroll
    for (int b = 0; b < 4; ++b) {
        #pragma unroll
        for (int s_ = 0; s_ < 4; ++s_) {
            float x0 = fmaxf(c1[b][4 * s_ + 0], 0.f);
            float x1 = fmaxf(c1[b][4 * s_ + 1], 0.f);
            float x2 = fmaxf(c1[b][4 * s_ + 2], 0.f);
            float x3 = fmaxf(c1[b][4 * s_ + 3], 0.f);
            __hip_bfloat162 p0 = __float22bfloat162_rn(make_float2(x0, x1));
            __hip_bfloat162 p1 = __float22bfloat162_rn(make_float2(x2, x3));
            uint2 w;
            w.x = *reinterpret_cast<unsigned int*>(&p0);
            w.y = *reinterpret_cast<unsigned int*>(&p1);
            *(uint2*)(myrow + 64 * b + 16 * s_ + 8 * h) = w;
        }
    }
    // same-wave LDS RAW: compiler inserts lgkmcnt wait; no cross-wave sharing.

    // GEMM2
    f32x16 c2;
    #pragma unroll
    for (int k = 0; k < 16; ++k) c2[k] = 0.0f;
    #pragma unroll
    for (int m = 0; m < 8; ++m) {
        uint2 lo = *(const uint2*)(myrow + 32 * m + 16 * h);
        uint2 hi = *(const uint2*)(myrow + 32 * m + 16 * h + 8);
        union { unsigned int u[4]; short8 s; } bf;
        bf.u[0] = lo.x; bf.u[1] = lo.y; bf.u[2] = hi.x; bf.u[3] = hi.y;
        c2 = __builtin_amdgcn_mfma_f32_32x32x16_bf16(a2[m], bf.s, c2, 0, 0, 0);
    }

    if (h == 0) {
        float pen = dist2 * scal[0];
        logitsT[0 * NE + e] = c2[0] + scal[1] - pen;
        logitsT[1 * NE + e] = c2[1] + scal[2] - pen;
        logitsT[2 * NE + e] = c2[2] + scal[3] - pen;
        logitsT[3 * NE + e] = c2[3] + scal[4] - pen;
    }
}

// ---------------------------------------------------------------------------
// attn (R6-proven): one wave per query. Sum pass stages unnormalized exp
// weights in LDS; phase B has no v_exp. Legacy inline-exp path for cnt > 256.
// ---------------------------------------------------------------------------
__global__ __launch_bounds__(256) void attn_kernel(const __hip_bfloat162* __restrict__ vb,
                                                   const float* __restrict__ logitsT,
                                                   const int* __restrict__ src,
                                                   const int* __restrict__ rp,
                                                   float* __restrict__ out) {
    __shared__ __align__(16) float wsh[4 * 4 * WCAP];   // 16896 B
    int t = threadIdx.x;
    int lane = t & 63, wave = t >> 6;
    int q = blockIdx.x * 4 + wave;
    int s0 = rp[q], s1 = rp[q + 1];
    int cnt = s1 - s0;
    int h = lane >> 4, i = lane & 15;
    const float* lp = logitsT + (size_t)h * NE;

    float m = -INFINITY;
    for (int e = s0 + i; e < s1; e += 16) m = fmaxf(m, lp[e]);
    #pragma unroll
    for (int off = 8; off; off >>= 1) m = fmaxf(m, __shfl_xor(m, off));

    float acc0 = 0.f, acc1 = 0.f, r;

    if (cnt <= 256) {
        int s0a = s0 & ~3;
        float* wpb = wsh + wave * (4 * WCAP) + h * WCAP;
        float sum = 0.f;
        for (int e = s0 + i; e < s1; e += 16) {
            float w = __expf(lp[e] - m);
            wpb[e - s0a] = w;
            sum += w;
        }
        #pragma unroll
        for (int off = 8; off; off >>= 1) sum += __shfl_xor(sum, off);
        r = 1.0f / (sum + 1e-16f);

        int e = s0;
        int e1 = (s0 + 3) & ~3; if (e1 > s1) e1 = s1;
        for (; e < e1; ++e) {
            float w = wpb[e - s0a];
            float2 f = __bfloat1622float2(vb[(size_t)src[e] * 64 + lane]);
            acc0 += w * f.x; acc1 += w * f.y;
        }
        for (; e + 4 <= s1; e += 4) {
            float4 w4 = *(const float4*)(wpb + (e - s0a));
            int4 s4 = *(const int4*)(src + e);
            float2 f0 = __bfloat1622float2(vb[(size_t)s4.x * 64 + lane]);
            float2 f1 = __bfloat1622float2(vb[(size_t)s4.y * 64 + lane]);
            float2 f2 = __bfloat1622float2(vb[(size_t)s4.z * 64 + lane]);
            float2 f3 = __bfloat1622float2(vb[(size_t)s4.w * 64 + lane]);
            acc0 += w4.x * f0.x + w4.y * f1.x + w4.z * f2.x + w4.w * f3.x;
            acc1 += w4.x * f0.y + w4.y * f1.y + w4.z * f2.y + w4.w * f3.y;
        }
        for (; e < s1; ++e) {
            float w = wpb[e - s0a];
            float2 f = __bfloat1622float2(vb[(size_t)src[e] * 64 + lane]);
            acc0 += w * f.x; acc1 += w * f.y;
        }
    } else {
        float sum = 0.f;
        for (int e = s0 + i; e < s1; e += 16) sum += __expf(lp[e] - m);
        #pragma unroll
        for (int off = 8; off; off >>= 1) sum += __shfl_xor(sum, off);
        r = 1.0f / (sum + 1e-16f);

        int e = s0;
        for (; e < s1 && (e & 3); ++e) {
            float w = __expf(lp[e] - m);
            float2 f = __bfloat1622float2(vb[(size_t)src[e] * 64 + lane]);
            acc0 += w * f.x; acc1 += w * f.y;
        }
        for (; e + 4 <= s1; e += 4) {
            float4 l4 = *(const float4*)(lp + e);
            int4 s4 = *(const int4*)(src + e);
            float w0 = __expf(l4.x - m);
            float w1 = __expf(l4.y - m);
            float w2 = __expf(l4.z - m);
            float w3 = __expf(l4.w - m);
            float2 f0 = __bfloat1622float2(vb[(size_t)s4.x * 64 + lane]);
            float2 f1 = __bfloat1622float2(vb[(size_t)s4.y * 64 + lane]);
            float2 f2 = __bfloat1622float2(vb[(size_t)s4.z * 64 + lane]);
            float2 f3 = __bfloat1622float2(vb[(size_t)s4.w * 64 + lane]);
            acc0 += w0 * f0.x + w1 * f1.x + w2 * f2.x + w3 * f3.x;
            acc1 += w0 * f0.y + w1 * f1.y + w2 * f2.y + w3 * f3.y;
        }
        for (; e < s1; ++e) {
            float w = __expf(lp[e] - m);
            float2 f = __bfloat1622float2(vb[(size_t)src[e] * 64 + lane]);
            acc0 += w * f.x; acc1 += w * f.y;
        }
    }
    *(float2*)(out + (size_t)q * 128 + lane * 2) = make_float2(acc0 * r, acc1 * r);
}

// ---------------------------------------------------------------------------
// ws layout: identical to the R1-R6-proven layout (high water 38,608,768 B).
// ---------------------------------------------------------------------------
extern "C" void kernel_launch(void* const* d_in, const int* in_sizes, int n_in,
                              void* d_out, int out_size, void* d_ws, size_t ws_size,
                              hipStream_t stream) {
    const float* h_obs     = (const float*)d_in[0];
    const float* pos_obs   = (const float*)d_in[1];
    const float* pos_query = (const float*)d_in[2];
    const int*   src       = (const int*)d_in[3];
    const int*   dst       = (const int*)d_in[4];
    const float* W1        = (const float*)d_in[5];
    const float* b1        = (const float*)d_in[6];
    const float* W2        = (const float*)d_in[7];
    const float* b2        = (const float*)d_in[8];
    const float* Wv        = (const float*)d_in[9];
    const float* bv        = (const float*)d_in[10];
    const float* log_sigma = (const float*)d_in[11];
    float* out = (float*)d_out;

    char* ws = (char*)d_ws;
    int*            rp      = (int*)(ws + 0);                   // 50001 ints  (end 200,004)
    float*          scal    = (float*)(ws + 200192);            // 8 floats    (end 200,224)
    unsigned short* W1cT    = (unsigned short*)(ws + 200256);   // 1024 bf16   (end 202,304)
    unsigned short* W2tb    = (unsigned short*)(ws + 202304);   // 512 bf16    (end 203,328)
    unsigned short* vbuf    = (unsigned short*)(ws + 208640);   // 6.4M bf16   (end 13,008,640)
    float*          logitsT = (float*)(ws + 13008768);          // 6.4M floats (end 38,608,768)

    hipLaunchKernelGGL(pack_kernel, dim3(1), dim3(256), 0, stream,
                       W1, b1, W2, b2, log_sigma, W1cT, W2tb, scal);
    hipLaunchKernelGGL(fusedVR_kernel, dim3(VP_BLOCKS + RP_BLOCKS), dim3(256), 0, stream,
                       dst, h_obs, Wv, bv, vbuf, rp);
    hipLaunchKernelGGL(edge_kernel, dim3(EDGE_BLOCKS), dim3(128), 0, stream,
                       pos_obs, pos_query, src, dst, W1cT, W2tb, scal, logitsT);
    hipLaunchKernelGGL(attn_kernel, dim3(N_Q / 4), dim3(256), 0, stream,
                       (const __hip_bfloat162*)vbuf, logitsT, src, rp, out);
}

// Round 11
// 247.384 us; speedup vs baseline: 1.9716x; 1.0064x over previous
//
#include <hip/hip_runtime.h>
#include <hip/hip_bf16.h>
#include <cstdint>
#include <cstddef>

#define N_O 50000
#define N_Q 50000
#define NE  1600000
// LATENT=128, HEADS=4, HEAD_DIM=32

#define EDGE_BLOCKS  (NE / 64)             // 25000 (2 waves x 32 edges, 128 thr)
#define VP_BLOCKS    ((N_O + 31) / 32)     // 1563  (32 rows per 128-thr block)
#define RP_BLOCKS    ((N_Q + 128) / 128)   // 391
#define WCAP 264                           // attn LDS plane stride (floats)

typedef __attribute__((ext_vector_type(8)))  short short8;
typedef __attribute__((ext_vector_type(16))) float f32x16;

__device__ inline unsigned short f2bf(float x) {
    __hip_bfloat16 hb = __float2bfloat16(x);
    return *reinterpret_cast<unsigned short*>(&hb);
}

// ---------------------------------------------------------------------------
// pack (R6/R10-proven): bf16 weight tensors for the MFMA edge MLP.
//  W1cT [128 hidden][8 attr] bf16 : attrs = [Wq+Wr (3), Wo-Wr (3), b1, 0]
//  W2tb [4 head][128 hidden] bf16
//  scal fp32: [0]=1/(2 sigma^2), [1..4]=b2
// ---------------------------------------------------------------------------
__global__ void pack_kernel(const float* __restrict__ W1, const float* __restrict__ b1,
                            const float* __restrict__ W2, const float* __restrict__ b2,
                            const float* __restrict__ log_sigma,
                            unsigned short* __restrict__ W1cT,
                            unsigned short* __restrict__ W2tb,
                            float* __restrict__ scal) {
    int j = threadIdx.x;
    if (j < 128) {
        #pragma unroll
        for (int a = 0; a < 3; ++a) {
            W1cT[j * 8 + a]     = f2bf(W1[(3 + a) * 128 + j] + W1[a * 128 + j]); // pq coef
            W1cT[j * 8 + 3 + a] = f2bf(W1[(6 + a) * 128 + j] - W1[a * 128 + j]); // po coef
        }
        W1cT[j * 8 + 6] = f2bf(b1[j]);
        W1cT[j * 8 + 7] = 0;
        #pragma unroll
        for (int hd = 0; hd < 4; ++hd)
            W2tb[hd * 128 + j] = f2bf(W2[j * 4 + hd]);
    } else if (j == 128) {
        float sigma = expf(log_sigma[0]) + 1e-6f;
        scal[0] = 1.0f / (2.0f * sigma * sigma);
        scal[1] = b2[0]; scal[2] = b2[1]; scal[3] = b2[2]; scal[4] = b2[3];
    }
}

// ---------------------------------------------------------------------------
// rowptr body (proven logic, 128-thread indexing): rp[q] = lower_bound(dst,q)
// ---------------------------------------------------------------------------
__device__ void rowptr_body(int bid, const int* __restrict__ dst, int* __restrict__ rp) {
    int q = bid * 128 + threadIdx.x;
    if (q > N_Q) return;
    int lo = 0, hi = NE;
    while (lo < hi) {
        int mid = (lo + hi) >> 1;
        if (dst[mid] < q) lo = mid + 1; else hi = mid;
    }
    rp[q] = lo;
}

// ---------------------------------------------------------------------------
// vproj body (proven 4x8-per-thread structure, re-indexed to 32 rows /
// 128 threads): v = h_obs @ Wv + bv, fp32 compute, bf16 output.
// LDS 32*132*4 = 16896 B.
// ---------------------------------------------------------------------------
__device__ void vproj_body(int bid, const float* __restrict__ h,
                           const float* __restrict__ Wv,
                           const float* __restrict__ bv,
                           unsigned short* __restrict__ v,
                           float* Ash /* 32*132 floats */) {
    int t = threadIdx.x;          // 0..127
    int n0 = bid * 32;
    #pragma unroll
    for (int rep = 0; rep < 8; ++rep) {
        int idx = rep * 128 + t;           // flat over [32][32] float4s
        int row = idx >> 5, c4 = (idx & 31) * 4;
        float4 val = make_float4(0.f, 0.f, 0.f, 0.f);
        if (n0 + row < N_O) val = *(const float4*)(h + (size_t)(n0 + row) * 128 + c4);
        float* d = &Ash[row * 132 + c4];
        d[0] = val.x; d[1] = val.y; d[2] = val.z; d[3] = val.w;
    }
    __syncthreads();

    int cg = t & 15, rg = t >> 4;          // 16 col groups x 8 row groups
    int c0 = cg * 8, r0 = rg * 4;
    float acc[4][8];
    #pragma unroll
    for (int i = 0; i < 4; ++i)
        #pragma unroll
        for (int j = 0; j < 8; ++j) acc[i][j] = 0.f;

    const float4* Wv4 = (const float4*)Wv;
    for (int k = 0; k < 128; ++k) {
        float4 b0 = Wv4[k * 32 + cg * 2];
        float4 b1v = Wv4[k * 32 + cg * 2 + 1];
        float bb[8] = {b0.x, b0.y, b0.z, b0.w, b1v.x, b1v.y, b1v.z, b1v.w};
        #pragma unroll
        for (int i = 0; i < 4; ++i) {
            float a = Ash[(r0 + i) * 132 + k];
            #pragma unroll
            for (int j = 0; j < 8; ++j) acc[i][j] += a * bb[j];
        }
    }

    float bvv[8];
    #pragma unroll
    for (int j = 0; j < 8; ++j) bvv[j] = bv[c0 + j];
    #pragma unroll
    for (int i = 0; i < 4; ++i) {
        int n = n0 + r0 + i;
        if (n < N_O) {
            uint4 o;
            __hip_bfloat162 t0 = __float22bfloat162_rn(
                make_float2(acc[i][0] + bvv[0], acc[i][1] + bvv[1]));
            __hip_bfloat162 t1 = __float22bfloat162_rn(
                make_float2(acc[i][2] + bvv[2], acc[i][3] + bvv[3]));
            __hip_bfloat162 t2 = __float22bfloat162_rn(
                make_float2(acc[i][4] + bvv[4], acc[i][5] + bvv[5]));
            __hip_bfloat162 t3 = __float22bfloat162_rn(
                make_float2(acc[i][6] + bvv[6], acc[i][7] + bvv[7]));
            o.x = *reinterpret_cast<unsigned int*>(&t0);
            o.y = *reinterpret_cast<unsigned int*>(&t1);
            o.z = *reinterpret_cast<unsigned int*>(&t2);
            o.w = *reinterpret_cast<unsigned int*>(&t3);
            *(uint4*)(v + (size_t)n * 128 + c0) = o;
        }
    }
}

// ---------------------------------------------------------------------------
// edge body (R10-proven, verbatim): one wave = 32 edges.
// GEMM1 (4x 32x32x16) -> relu/bf16 -> per-wave LDS tile [32][264 B]
// -> GEMM2 (8x 32x32x16, K=128). 2 waves/block, LDS 16896 B.
// ---------------------------------------------------------------------------
__device__ void edge_body(int bid, const float* __restrict__ pos_obs,
                          const float* __restrict__ pos_query,
                          const int* __restrict__ src, const int* __restrict__ dst,
                          const unsigned short* __restrict__ W1cT,
                          const unsigned short* __restrict__ W2tb,
                          const float* __restrict__ scal,
                          float* __restrict__ logitsT,
                          unsigned char* smem /* 2*8448 B */) {
    int t = threadIdx.x;
    int wave = t >> 6, lane = t & 63;
    int i = lane & 31, h = lane >> 5;
    unsigned char* myrow = smem + wave * 8448 + i * 264;

    short8 zero8;
    #pragma unroll
    for (int k = 0; k < 8; ++k) zero8[k] = 0;

    short8 a1[4];
    #pragma unroll
    for (int b = 0; b < 4; ++b)
        a1[b] = (h == 0) ? *(const short8*)(W1cT + (32 * b + i) * 8) : zero8;

    short8 a2[8];
    #pragma unroll
    for (int m = 0; m < 8; ++m)
        a2[m] = (i < 4) ? *(const short8*)(W2tb + i * 128 + m * 16 + h * 8) : zero8;

    int e = bid * 64 + wave * 32 + i;
    int s = src[e], d = dst[e];
    float pox = pos_obs[s * 3 + 0], poy = pos_obs[s * 3 + 1], poz = pos_obs[s * 3 + 2];
    float pqx = pos_query[d * 3 + 0], pqy = pos_query[d * 3 + 1], pqz = pos_query[d * 3 + 2];
    float rx = pqx - pox, ry = pqy - poy, rz = pqz - poz;
    float dist2 = rx * rx + ry * ry + rz * rz;

    short8 bea = zero8;
    if (h == 0) {
        bea[0] = (short)f2bf(pqx); bea[1] = (short)f2bf(pqy); bea[2] = (short)f2bf(pqz);
        bea[3] = (short)f2bf(pox); bea[4] = (short)f2bf(poy); bea[5] = (short)f2bf(poz);
        bea[6] = (short)0x3F80;    // 1.0 bf16 (bias attr)
        bea[7] = 0;
    }

    // GEMM1
    f32x16 c1[4];
    #pragma unroll
    for (int b = 0; b < 4; ++b) {
        #pragma unroll
        for (int k = 0; k < 16; ++k) c1[b][k] = 0.0f;
        c1[b] = __builtin_amdgcn_mfma_f32_32x32x16_bf16(a1[b], bea, c1[b], 0, 0, 0);
    }

    // relu -> bf16 -> LDS  (reg r+4s -> hidden 32b + 8s + 4h + r)
    #pragma unroll
    for (int b = 0; b < 4; ++b) {
        #pragma unroll
        for (int s_ = 0; s_ < 4; ++s_) {
            float x0 = fmaxf(c1[b][4 * s_ + 0], 0.f);
            float x1 = fmaxf(c1[b][4 * s_ + 1], 0.f);
            float x2 = fmaxf(c1[b][4 * s_ + 2], 0.f);
            float x3 = fmaxf(c1[b][4 * s_ + 3], 0.f);
            __hip_bfloat162 p0 = __float22bfloat162_rn(make_float2(x0, x1));
            __hip_bfloat162 p1 = __float22bfloat162_rn(make_float2(x2, x3));
            uint2 w;
            w.x = *reinterpret_cast<unsigned int*>(&p0);
            w.y = *reinterpret_cast<unsigned int*>(&p1);
            *(uint2*)(myrow + 64 * b + 16 * s_ + 8 * h) = w;
        }
    }
    // same-wave LDS RAW: compiler inserts lgkmcnt wait; no cross-wave sharing.

    // GEMM2
    f32x16 c2;
    #pragma unroll
    for (int k = 0; k < 16; ++k) c2[k] = 0.0f;
    #pragma unroll
    for (int m = 0; m < 8; ++m) {
        uint2 lo = *(const uint2*)(myrow + 32 * m + 16 * h);
        uint2 hi = *(const uint2*)(myrow + 32 * m + 16 * h + 8);
        union { unsigned int u[4]; short8 s; } bf;
        bf.u[0] = lo.x; bf.u[1] = lo.y; bf.u[2] = hi.x; bf.u[3] = hi.y;
        c2 = __builtin_amdgcn_mfma_f32_32x32x16_bf16(a2[m], bf.s, c2, 0, 0, 0);
    }

    if (h == 0) {
        float pen = dist2 * scal[0];
        logitsT[0 * NE + e] = c2[0] + scal[1] - pen;
        logitsT[1 * NE + e] = c2[1] + scal[2] - pen;
        logitsT[2 * NE + e] = c2[2] + scal[3] - pen;
        logitsT[3 * NE + e] = c2[3] + scal[4] - pen;
    }
}

// ---------------------------------------------------------------------------
// fused: edge | vproj | rowptr partitioned by blockIdx (mutually
// independent). 128 threads, 16896 B LDS -> ~18 waves/CU (vs R6's 9).
// ---------------------------------------------------------------------------
__global__ __launch_bounds__(128) void fused_kernel(
        const float* __restrict__ pos_obs, const float* __restrict__ pos_query,
        const int* __restrict__ src, const int* __restrict__ dst,
        const unsigned short* __restrict__ W1cT,
        const unsigned short* __restrict__ W2tb,
        const float* __restrict__ scal, float* __restrict__ logitsT,
        const float* __restrict__ h_obs, const float* __restrict__ Wv,
        const float* __restrict__ bv, unsigned short* __restrict__ vbuf,
        int* __restrict__ rp) {
    __shared__ __align__(16) unsigned char smem[16896];  // 2*8448 == 32*132*4
    int b = blockIdx.x;
    if (b < EDGE_BLOCKS) {
        edge_body(b, pos_obs, pos_query, src, dst, W1cT, W2tb, scal, logitsT, smem);
    } else if (b < EDGE_BLOCKS + VP_BLOCKS) {
        vproj_body(b - EDGE_BLOCKS, h_obs, Wv, bv, vbuf, (float*)smem);
    } else {
        rowptr_body(b - EDGE_BLOCKS - VP_BLOCKS, dst, rp);
    }
}

// ---------------------------------------------------------------------------
// attn (R10-proven, verbatim): one wave per query; LDS-staged exp weights.
// ---------------------------------------------------------------------------
__global__ __launch_bounds__(256) void attn_kernel(const __hip_bfloat162* __restrict__ vb,
                                                   const float* __restrict__ logitsT,
                                                   const int* __restrict__ src,
                                                   const int* __restrict__ rp,
                                                   float* __restrict__ out) {
    __shared__ __align__(16) float wsh[4 * 4 * WCAP];   // 16896 B
    int t = threadIdx.x;
    int lane = t & 63, wave = t >> 6;
    int q = blockIdx.x * 4 + wave;
    int s0 = rp[q], s1 = rp[q + 1];
    int cnt = s1 - s0;
    int h = lane >> 4, i = lane & 15;
    const float* lp = logitsT + (size_t)h * NE;

    float m = -INFINITY;
    for (int e = s0 + i; e < s1; e += 16) m = fmaxf(m, lp[e]);
    #pragma unroll
    for (int off = 8; off; off >>= 1) m = fmaxf(m, __shfl_xor(m, off));

    float acc0 = 0.f, acc1 = 0.f, r;

    if (cnt <= 256) {
        int s0a = s0 & ~3;
        float* wpb = wsh + wave * (4 * WCAP) + h * WCAP;
        float sum = 0.f;
        for (int e = s0 + i; e < s1; e += 16) {
            float w = __expf(lp[e] - m);
            wpb[e - s0a] = w;
            sum += w;
        }
        #pragma unroll
        for (int off = 8; off; off >>= 1) sum += __shfl_xor(sum, off);
        r = 1.0f / (sum + 1e-16f);

        int e = s0;
        int e1 = (s0 + 3) & ~3; if (e1 > s1) e1 = s1;
        for (; e < e1; ++e) {
            float w = wpb[e - s0a];
            float2 f = __bfloat1622float2(vb[(size_t)src[e] * 64 + lane]);
            acc0 += w * f.x; acc1 += w * f.y;
        }
        for (; e + 4 <= s1; e += 4) {
            float4 w4 = *(const float4*)(wpb + (e - s0a));
            int4 s4 = *(const int4*)(src + e);
            float2 f0 = __bfloat1622float2(vb[(size_t)s4.x * 64 + lane]);
            float2 f1 = __bfloat1622float2(vb[(size_t)s4.y * 64 + lane]);
            float2 f2 = __bfloat1622float2(vb[(size_t)s4.z * 64 + lane]);
            float2 f3 = __bfloat1622float2(vb[(size_t)s4.w * 64 + lane]);
            acc0 += w4.x * f0.x + w4.y * f1.x + w4.z * f2.x + w4.w * f3.x;
            acc1 += w4.x * f0.y + w4.y * f1.y + w4.z * f2.y + w4.w * f3.y;
        }
        for (; e < s1; ++e) {
            float w = wpb[e - s0a];
            float2 f = __bfloat1622float2(vb[(size_t)src[e] * 64 + lane]);
            acc0 += w * f.x; acc1 += w * f.y;
        }
    } else {
        float sum = 0.f;
        for (int e = s0 + i; e < s1; e += 16) sum += __expf(lp[e] - m);
        #pragma unroll
        for (int off = 8; off; off >>= 1) sum += __shfl_xor(sum, off);
        r = 1.0f / (sum + 1e-16f);

        int e = s0;
        for (; e < s1 && (e & 3); ++e) {
            float w = __expf(lp[e] - m);
            float2 f = __bfloat1622float2(vb[(size_t)src[e] * 64 + lane]);
            acc0 += w * f.x; acc1 += w * f.y;
        }
        for (; e + 4 <= s1; e += 4) {
            float4 l4 = *(const float4*)(lp + e);
            int4 s4 = *(const int4*)(src + e);
            float w0 = __expf(l4.x - m);
            float w1 = __expf(l4.y - m);
            float w2 = __expf(l4.z - m);
            float w3 = __expf(l4.w - m);
            float2 f0 = __bfloat1622float2(vb[(size_t)s4.x * 64 + lane]);
            float2 f1 = __bfloat1622float2(vb[(size_t)s4.y * 64 + lane]);
            float2 f2 = __bfloat1622float2(vb[(size_t)s4.z * 64 + lane]);
            float2 f3 = __bfloat1622float2(vb[(size_t)s4.w * 64 + lane]);
            acc0 += w0 * f0.x + w1 * f1.x + w2 * f2.x + w3 * f3.x;
            acc1 += w0 * f0.y + w1 * f1.y + w2 * f2.y + w3 * f3.y;
        }
        for (; e < s1; ++e) {
            float w = __expf(lp[e] - m);
            float2 f = __bfloat1622float2(vb[(size_t)src[e] * 64 + lane]);
            acc0 += w * f.x; acc1 += w * f.y;
        }
    }
    *(float2*)(out + (size_t)q * 128 + lane * 2) = make_float2(acc0 * r, acc1 * r);
}

// ---------------------------------------------------------------------------
// ws layout: identical to the R1-R6/R10-proven layout (high water 38,608,768 B).
// ---------------------------------------------------------------------------
extern "C" void kernel_launch(void* const* d_in, const int* in_sizes, int n_in,
                              void* d_out, int out_size, void* d_ws, size_t ws_size,
                              hipStream_t stream) {
    const float* h_obs     = (const float*)d_in[0];
    const float* pos_obs   = (const float*)d_in[1];
    const float* pos_query = (const float*)d_in[2];
    const int*   src       = (const int*)d_in[3];
    const int*   dst       = (const int*)d_in[4];
    const float* W1        = (const float*)d_in[5];
    const float* b1        = (const float*)d_in[6];
    const float* W2        = (const float*)d_in[7];
    const float* b2        = (const float*)d_in[8];
    const float* Wv        = (const float*)d_in[9];
    const float* bv        = (const float*)d_in[10];
    const float* log_sigma = (const float*)d_in[11];
    float* out = (float*)d_out;

    char* ws = (char*)d_ws;
    int*            rp      = (int*)(ws + 0);                   // 50001 ints  (end 200,004)
    float*          scal    = (float*)(ws + 200192);            // 8 floats    (end 200,224)
    unsigned short* W1cT    = (unsigned short*)(ws + 200256);   // 1024 bf16   (end 202,304)
    unsigned short* W2tb    = (unsigned short*)(ws + 202304);   // 512 bf16    (end 203,328)
    unsigned short* vbuf    = (unsigned short*)(ws + 208640);   // 6.4M bf16   (end 13,008,640)
    float*          logitsT = (float*)(ws + 13008768);          // 6.4M floats (end 38,608,768)

    hipLaunchKernelGGL(pack_kernel, dim3(1), dim3(256), 0, stream,
                       W1, b1, W2, b2, log_sigma, W1cT, W2tb, scal);
    hipLaunchKernelGGL(fused_kernel, dim3(EDGE_BLOCKS + VP_BLOCKS + RP_BLOCKS),
                       dim3(128), 0, stream,
                       pos_obs, pos_query, src, dst, W1cT, W2tb, scal, logitsT,
                       h_obs, Wv, bv, vbuf, rp);
    hipLaunchKernelGGL(attn_kernel, dim3(N_Q / 4), dim3(256), 0, stream,
                       (const __hip_bfloat162*)vbuf, logitsT, src, rp, out);
}